// Round 2
// baseline (1007.546 us; speedup 1.0000x reference)
//
#include <hip/hip_runtime.h>
#include <hip/hip_bf16.h>

// ---------------------------------------------------------------------------
// 2-layer GAT on MI355X (gfx950).
// Float tensors may arrive as bf16 OR fp32 (harness-dependent): we detect the
// dtype per-tensor on device (no host sync -> graph-capture safe) and branch
// uniformly. edge_index is int32 per harness contract.
// Pipeline: detect -> cvt weights -> CSR-by-dst -> GEMM1 -> alpha1 ->
//           agg1(+bias+GELU) -> GEMM2 -> alpha2 -> agg2(+bias) -> out.
// Intermediates: h1,g bf16 (halve gather traffic), h2 fp32 (final accuracy).
// ---------------------------------------------------------------------------

#define IN_DIM   256
#define HID      256
#define HEADS    4
#define C1       64
#define OUT_DIM  128
#define NEG_SLOPE 0.2f

__device__ __forceinline__ float loadf(const void* p, size_t i, int isbf16) {
    return isbf16 ? __bfloat162float(((const __hip_bfloat16*)p)[i])
                  : ((const float*)p)[i];
}

// ---------------- dtype detection ----------------
// Sample up to 4096 halfwords; plausible-bf16 = zero or exponent in [90,140].
// True bf16 data ~100% plausible; fp32 read as bf16 ~60%. Threshold 80%.
__global__ void detect_kernel(const void* p, int n, int* flag) {
    const unsigned short* u = (const unsigned short*)p;
    int nslots = n < 4096 ? n : 4096;
    int cnt = 0;
    for (int i = threadIdx.x; i < nslots; i += 256) {
        unsigned short a = u[i] & 0x7FFF;
        int e = a >> 7;
        if (a == 0 || (e >= 90 && e <= 140)) cnt++;
    }
    __shared__ int red[4];
    for (int o = 32; o > 0; o >>= 1) cnt += __shfl_down(cnt, o);
    if ((threadIdx.x & 63) == 0) red[threadIdx.x >> 6] = cnt;
    __syncthreads();
    if (threadIdx.x == 0) {
        int tot = red[0] + red[1] + red[2] + red[3];
        flag[0] = (tot * 10 >= nslots * 8) ? 1 : 0;
    }
}

__global__ void cvt_kernel(const void* src, const int* flag, float* dst, int n) {
    int i = blockIdx.x * blockDim.x + threadIdx.x;
    if (i >= n) return;
    dst[i] = loadf(src, i, *flag);
}

// ---------------- CSR build ----------------

__global__ void count_kernel(const int* __restrict__ ei, int E, int EP,
                             int* __restrict__ deg) {
    int idx = blockIdx.x * blockDim.x + threadIdx.x;
    if (idx >= EP) return;
    int d = (idx < E) ? ei[E + idx] : (idx - E);
    atomicAdd(&deg[d], 1);
}

__global__ void scan_kernel(const int* __restrict__ deg, int* __restrict__ offs,
                            int* __restrict__ cursor, int n) {
    __shared__ int partial[1024];
    int t = threadIdx.x;
    int chunk = (n + 1023) >> 10;
    int begin = t * chunk;
    int end   = begin + chunk; if (end > n) end = n;
    int s = 0;
    for (int i = begin; i < end; ++i) s += deg[i];
    partial[t] = s;
    __syncthreads();
    for (int d = 1; d < 1024; d <<= 1) {
        int v = (t >= d) ? partial[t - d] : 0;
        __syncthreads();
        partial[t] += v;
        __syncthreads();
    }
    int run = (t == 0) ? 0 : partial[t - 1];
    for (int i = begin; i < end; ++i) {
        offs[i] = run;
        cursor[i] = run;
        run += deg[i];
    }
    if (t == 1023) offs[n] = partial[1023];
}

__global__ void fill_kernel(const int* __restrict__ ei, int E, int EP,
                            int* __restrict__ cursor, int* __restrict__ ssrc) {
    int idx = blockIdx.x * blockDim.x + threadIdx.x;
    if (idx >= EP) return;
    int src = (idx < E) ? ei[idx]     : (idx - E);
    int dst = (idx < E) ? ei[E + idx] : (idx - E);
    int pos = atomicAdd(&cursor[dst], 1);
    ssrc[pos] = src;
}

// ---------------- GEMM: C[M,Nn] = A[M,K] @ B[K,Nn] ----------------
// A dtype via runtime flag (nullptr flag => bf16); B fp32; OutT = bf16|float.

__device__ __forceinline__ void store_out(float* C, size_t i, float v) { C[i] = v; }
__device__ __forceinline__ void store_out(__hip_bfloat16* C, size_t i, float v) {
    C[i] = __float2bfloat16(v);
}

template <typename OutT>
__global__ __launch_bounds__(256) void gemm_kernel(const void* __restrict__ A,
                                                   const int* aflagp,
                                                   const float* __restrict__ B,
                                                   OutT* __restrict__ C,
                                                   int M, int Nn, int K) {
    const int aflag = aflagp ? *aflagp : 1;
    constexpr int BM = 128, BN = 128, BK = 16;
    __shared__ float As[BK][BM + 4];
    __shared__ float Bs[BK][BN + 4];

    int tid = threadIdx.x;
    int tx = tid & 15;
    int ty = tid >> 4;
    int bm = blockIdx.y * BM;
    int bn = blockIdx.x * BN;

    float acc[8][8];
#pragma unroll
    for (int i = 0; i < 8; ++i)
#pragma unroll
        for (int j = 0; j < 8; ++j) acc[i][j] = 0.f;

    for (int k0 = 0; k0 < K; k0 += BK) {
#pragma unroll
        for (int l = tid; l < BM * BK; l += 256) {
            int kk = l & (BK - 1);
            int m  = l >> 4;
            int row = bm + m;
            float v = 0.f;
            if (row < M) v = loadf(A, (size_t)row * K + k0 + kk, aflag);
            As[kk][m] = v;
        }
#pragma unroll
        for (int l = tid; l < BK * BN; l += 256) {
            int n  = l & (BN - 1);
            int kk = l >> 7;
            Bs[kk][n] = B[(size_t)(k0 + kk) * Nn + bn + n];
        }
        __syncthreads();

#pragma unroll
        for (int kk = 0; kk < BK; ++kk) {
            float a[8], b[8];
#pragma unroll
            for (int i = 0; i < 8; ++i) a[i] = As[kk][ty * 8 + i];
#pragma unroll
            for (int j = 0; j < 8; ++j) b[j] = Bs[kk][tx * 8 + j];
#pragma unroll
            for (int i = 0; i < 8; ++i)
#pragma unroll
                for (int j = 0; j < 8; ++j) acc[i][j] += a[i] * b[j];
        }
        __syncthreads();
    }

#pragma unroll
    for (int i = 0; i < 8; ++i) {
        int row = bm + ty * 8 + i;
        if (row >= M) continue;
        size_t base = (size_t)row * Nn + bn + tx * 8;
#pragma unroll
        for (int j = 0; j < 8; ++j) store_out(C, base + j, acc[i][j]);
    }
}

// ---------------- attention scalar products ----------------

__global__ void alpha1_kernel(const __hip_bfloat16* __restrict__ h1,
                              const float* __restrict__ asw,
                              const float* __restrict__ adw,
                              float* __restrict__ as1, float* __restrict__ ad1,
                              int n) {
    int gt = blockIdx.x * blockDim.x + threadIdx.x;
    int v = gt >> 6;
    int lane = gt & 63;
    if (v >= n) return;
#pragma unroll
    for (int h = 0; h < HEADS; ++h) {
        float val = __bfloat162float(h1[(size_t)v * HID + h * C1 + lane]);
        float s = val * asw[h * C1 + lane];
        float d = val * adw[h * C1 + lane];
#pragma unroll
        for (int o = 32; o > 0; o >>= 1) {
            s += __shfl_down(s, o);
            d += __shfl_down(d, o);
        }
        if (lane == 0) {
            as1[v * HEADS + h] = s;
            ad1[v * HEADS + h] = d;
        }
    }
}

__global__ void alpha2_kernel(const float* __restrict__ h2,
                              const float* __restrict__ asw,
                              const float* __restrict__ adw,
                              float* __restrict__ as2, float* __restrict__ ad2,
                              int n) {
    int gt = blockIdx.x * blockDim.x + threadIdx.x;
    int v = gt >> 6;
    int lane = gt & 63;
    if (v >= n) return;
    float v0 = h2[(size_t)v * OUT_DIM + lane];
    float v1 = h2[(size_t)v * OUT_DIM + 64 + lane];
    float s = v0 * asw[lane] + v1 * asw[64 + lane];
    float d = v0 * adw[lane] + v1 * adw[64 + lane];
#pragma unroll
    for (int o = 32; o > 0; o >>= 1) {
        s += __shfl_down(s, o);
        d += __shfl_down(d, o);
    }
    if (lane == 0) { as2[v] = s; ad2[v] = d; }
}

// ---------------- aggregation (node-parallel, no atomics) ----------------

__device__ __forceinline__ float leaky(float a) {
    return a > 0.f ? a : NEG_SLOPE * a;
}

__global__ __launch_bounds__(256) void agg1_kernel(
    const __hip_bfloat16* __restrict__ h1, const float* __restrict__ as1,
    const float* __restrict__ ad1, const int* __restrict__ offs,
    const int* __restrict__ ssrc, const float* __restrict__ bias1,
    __hip_bfloat16* __restrict__ g, int n) {
    int v = blockIdx.x;
    int tid = threadIdx.x;
    int head = tid >> 6;
    int start = offs[v], end = offs[v + 1];
    float adv = ad1[v * HEADS + head];

    float m = -1e30f;
    for (int i = start; i < end; ++i) {
        int s = ssrc[i];
        float e = leaky(as1[s * HEADS + head] + adv);
        m = fmaxf(m, e);
    }
    float num = 0.f, den = 0.f;
    for (int i = start; i < end; ++i) {
        int s = ssrc[i];
        float e = leaky(as1[s * HEADS + head] + adv);
        float w = __expf(e - m);
        den += w;
        num += w * __bfloat162float(h1[(size_t)s * HID + tid]);
    }
    float o = num / (den + 1e-16f) + bias1[tid];
    float ge = 0.5f * o * (1.0f + erff(o * 0.70710678118654752440f));
    g[(size_t)v * HID + tid] = __float2bfloat16(ge);
}

__global__ __launch_bounds__(128) void agg2_kernel(
    const float* __restrict__ h2, const float* __restrict__ as2,
    const float* __restrict__ ad2, const int* __restrict__ offs,
    const int* __restrict__ ssrc, const float* __restrict__ bias2,
    void* __restrict__ out, const int* outflagp, int n) {
    int v = blockIdx.x;
    int tid = threadIdx.x;
    int outbf = *outflagp;
    int start = offs[v], end = offs[v + 1];
    float adv = ad2[v];

    float m = -1e30f;
    for (int i = start; i < end; ++i) {
        int s = ssrc[i];
        float e = leaky(as2[s] + adv);
        m = fmaxf(m, e);
    }
    float num = 0.f, den = 0.f;
    for (int i = start; i < end; ++i) {
        int s = ssrc[i];
        float e = leaky(as2[s] + adv);
        float w = __expf(e - m);
        den += w;
        num += w * h2[(size_t)s * OUT_DIM + tid];
    }
    float o = num / (den + 1e-16f) + bias2[tid];
    size_t oi = (size_t)v * OUT_DIM + tid;
    if (outbf) ((__hip_bfloat16*)out)[oi] = __float2bfloat16(o);
    else       ((float*)out)[oi] = o;
}

// ---------------------------------------------------------------------------

extern "C" void kernel_launch(void* const* d_in, const int* in_sizes, int n_in,
                              void* d_out, int out_size, void* d_ws, size_t ws_size,
                              hipStream_t stream) {
    const void* x    = d_in[0];
    const int*  ei   = (const int*)d_in[1];
    const void* W1   = d_in[2];
    const void* as1w = d_in[3];
    const void* ad1w = d_in[4];
    const void* b1   = d_in[5];
    const void* W2   = d_in[6];
    const void* as2w = d_in[7];
    const void* ad2w = d_in[8];
    const void* b2   = d_in[9];

    const int N  = out_size / OUT_DIM;       // 50000
    const int E  = in_sizes[1] / 2;          // 800000
    const int EP = E + N;

    // ---- workspace carve (4-byte aligned first, bf16 last) ----
    float* W1f   = (float*)d_ws;                       // 65536
    float* W2f   = W1f + IN_DIM * HID;                 // 32768
    float* as1wf = W2f + HID * OUT_DIM;                // 256
    float* ad1wf = as1wf + HEADS * C1;                 // 256
    float* b1f   = ad1wf + HEADS * C1;                 // 256
    float* as2wf = b1f + HID;                          // 128
    float* ad2wf = as2wf + OUT_DIM;                    // 128
    float* b2f   = ad2wf + OUT_DIM;                    // 128
    float* h2    = b2f + OUT_DIM;                      // N*128
    float* as1   = h2 + (size_t)N * OUT_DIM;           // N*4
    float* ad1   = as1 + (size_t)N * HEADS;            // N*4
    float* as2   = ad1 + (size_t)N * HEADS;            // N
    float* ad2   = as2 + (size_t)N;                    // N
    int*   flags = (int*)(ad2 + (size_t)N);            // 16
    int*   deg    = flags + 16;                        // N
    int*   offs   = deg + N;                           // N+1
    int*   cursor = offs + N + 1;                      // N
    int*   ssrc   = cursor + N;                        // EP
    __hip_bfloat16* h1 = (__hip_bfloat16*)(ssrc + EP); // N*256
    __hip_bfloat16* g  = h1 + (size_t)N * HID;         // N*256

    // ---- dtype detection (device-side, capture-safe) ----
    detect_kernel<<<1, 256, 0, stream>>>(x,    in_sizes[0], flags + 0);
    detect_kernel<<<1, 256, 0, stream>>>(W1,   in_sizes[2], flags + 1);
    detect_kernel<<<1, 256, 0, stream>>>(as1w, in_sizes[3], flags + 2);
    detect_kernel<<<1, 256, 0, stream>>>(ad1w, in_sizes[4], flags + 3);
    detect_kernel<<<1, 256, 0, stream>>>(b1,   in_sizes[5], flags + 4);
    detect_kernel<<<1, 256, 0, stream>>>(W2,   in_sizes[6], flags + 5);
    detect_kernel<<<1, 256, 0, stream>>>(as2w, in_sizes[7], flags + 6);
    detect_kernel<<<1, 256, 0, stream>>>(ad2w, in_sizes[8], flags + 7);
    detect_kernel<<<1, 256, 0, stream>>>(b2,   in_sizes[9], flags + 8);

    // ---- convert small tensors to fp32 ----
    cvt_kernel<<<(IN_DIM * HID + 255) / 256, 256, 0, stream>>>(W1, flags + 1, W1f, IN_DIM * HID);
    cvt_kernel<<<1, 256, 0, stream>>>(as1w, flags + 2, as1wf, HEADS * C1);
    cvt_kernel<<<1, 256, 0, stream>>>(ad1w, flags + 3, ad1wf, HEADS * C1);
    cvt_kernel<<<1, 256, 0, stream>>>(b1,   flags + 4, b1f,   HID);
    cvt_kernel<<<(HID * OUT_DIM + 255) / 256, 256, 0, stream>>>(W2, flags + 5, W2f, HID * OUT_DIM);
    cvt_kernel<<<1, 256, 0, stream>>>(as2w, flags + 6, as2wf, OUT_DIM);
    cvt_kernel<<<1, 256, 0, stream>>>(ad2w, flags + 7, ad2wf, OUT_DIM);
    cvt_kernel<<<1, 256, 0, stream>>>(b2,   flags + 8, b2f,   OUT_DIM);

    // ---- CSR build ----
    hipMemsetAsync(deg, 0, (size_t)N * sizeof(int), stream);
    {
        int blk = 256, grd = (EP + blk - 1) / blk;
        count_kernel<<<grd, blk, 0, stream>>>(ei, E, EP, deg);
        scan_kernel<<<1, 1024, 0, stream>>>(deg, offs, cursor, N);
        fill_kernel<<<grd, blk, 0, stream>>>(ei, E, EP, cursor, ssrc);
    }

    // ---- layer 1 ----
    {
        dim3 grd(HID / 128, (N + 127) / 128);
        gemm_kernel<__hip_bfloat16><<<grd, 256, 0, stream>>>(x, flags + 0, W1f, h1, N, HID, IN_DIM);
    }
    alpha1_kernel<<<((N * 64) + 255) / 256, 256, 0, stream>>>(h1, as1wf, ad1wf, as1, ad1, N);
    agg1_kernel<<<N, 256, 0, stream>>>(h1, as1, ad1, offs, ssrc, b1f, g, N);

    // ---- layer 2 ----
    {
        dim3 grd(OUT_DIM / 128, (N + 127) / 128);
        gemm_kernel<float><<<grd, 256, 0, stream>>>(g, nullptr, W2f, h2, N, OUT_DIM, HID);
    }
    alpha2_kernel<<<((N * 64) + 255) / 256, 256, 0, stream>>>(h2, as2wf, ad2wf, as2, ad2, N);
    agg2_kernel<<<N, 128, 0, stream>>>(h2, as2, ad2, offs, ssrc, b2f, d_out, flags + 0, N);
}

// Round 3
// 894.540 us; speedup vs baseline: 1.1263x; 1.1263x over previous
//
#include <hip/hip_runtime.h>
#include <hip/hip_bf16.h>

// ---------------------------------------------------------------------------
// 2-layer GAT on MI355X (gfx950).
// R2: softmax factored out of the channel-parallel aggregation loops.
//   attn1/attn2 (wave-per-node) compute normalized alpha per (edge,head);
//   agg1v/agg2v are pure weighted gathers (bf16x2 / float2 per thread).
// Float tensors may arrive bf16 OR fp32: detected on device (capture-safe).
// ---------------------------------------------------------------------------

#define IN_DIM   256
#define HID      256
#define HEADS    4
#define C1       64
#define OUT_DIM  128
#define NEG_SLOPE 0.2f

__device__ __forceinline__ float loadf(const void* p, size_t i, int isbf16) {
    return isbf16 ? __bfloat162float(((const __hip_bfloat16*)p)[i])
                  : ((const float*)p)[i];
}

__device__ __forceinline__ float leaky(float a) {
    return a > 0.f ? a : NEG_SLOPE * a;
}

// ---------------- dtype detection ----------------
__global__ void detect_kernel(const void* p, int n, int* flag) {
    const unsigned short* u = (const unsigned short*)p;
    int nslots = n < 4096 ? n : 4096;
    int cnt = 0;
    for (int i = threadIdx.x; i < nslots; i += 256) {
        unsigned short a = u[i] & 0x7FFF;
        int e = a >> 7;
        if (a == 0 || (e >= 90 && e <= 140)) cnt++;
    }
    __shared__ int red[4];
    for (int o = 32; o > 0; o >>= 1) cnt += __shfl_down(cnt, o);
    if ((threadIdx.x & 63) == 0) red[threadIdx.x >> 6] = cnt;
    __syncthreads();
    if (threadIdx.x == 0) {
        int tot = red[0] + red[1] + red[2] + red[3];
        flag[0] = (tot * 10 >= nslots * 8) ? 1 : 0;
    }
}

__global__ void cvt_kernel(const void* src, const int* flag, float* dst, int n) {
    int i = blockIdx.x * blockDim.x + threadIdx.x;
    if (i >= n) return;
    dst[i] = loadf(src, i, *flag);
}

// ---------------- CSR build ----------------

__global__ void count_kernel(const int* __restrict__ ei, int E, int EP,
                             int* __restrict__ deg) {
    int idx = blockIdx.x * blockDim.x + threadIdx.x;
    if (idx >= EP) return;
    int d = (idx < E) ? ei[E + idx] : (idx - E);
    atomicAdd(&deg[d], 1);
}

__global__ void scan_kernel(const int* __restrict__ deg, int* __restrict__ offs,
                            int* __restrict__ cursor, int n) {
    __shared__ int partial[1024];
    int t = threadIdx.x;
    int chunk = (n + 1023) >> 10;
    int begin = t * chunk;
    int end   = begin + chunk; if (end > n) end = n;
    int s = 0;
    for (int i = begin; i < end; ++i) s += deg[i];
    partial[t] = s;
    __syncthreads();
    for (int d = 1; d < 1024; d <<= 1) {
        int v = (t >= d) ? partial[t - d] : 0;
        __syncthreads();
        partial[t] += v;
        __syncthreads();
    }
    int run = (t == 0) ? 0 : partial[t - 1];
    for (int i = begin; i < end; ++i) {
        offs[i] = run;
        cursor[i] = run;
        run += deg[i];
    }
    if (t == 1023) offs[n] = partial[1023];
}

__global__ void fill_kernel(const int* __restrict__ ei, int E, int EP,
                            int* __restrict__ cursor, int* __restrict__ ssrc) {
    int idx = blockIdx.x * blockDim.x + threadIdx.x;
    if (idx >= EP) return;
    int src = (idx < E) ? ei[idx]     : (idx - E);
    int dst = (idx < E) ? ei[E + idx] : (idx - E);
    int pos = atomicAdd(&cursor[dst], 1);
    ssrc[pos] = src;
}

// ---------------- GEMM: C[M,Nn] = A[M,K] @ B[K,Nn] ----------------

__device__ __forceinline__ void store_out(float* C, size_t i, float v) { C[i] = v; }
__device__ __forceinline__ void store_out(__hip_bfloat16* C, size_t i, float v) {
    C[i] = __float2bfloat16(v);
}

template <typename OutT>
__global__ __launch_bounds__(256) void gemm_kernel(const void* __restrict__ A,
                                                   const int* aflagp,
                                                   const float* __restrict__ B,
                                                   OutT* __restrict__ C,
                                                   int M, int Nn, int K) {
    const int aflag = aflagp ? *aflagp : 1;
    constexpr int BM = 128, BN = 128, BK = 16;
    __shared__ float As[BK][BM + 4];
    __shared__ float Bs[BK][BN + 4];

    int tid = threadIdx.x;
    int tx = tid & 15;
    int ty = tid >> 4;
    int bm = blockIdx.y * BM;
    int bn = blockIdx.x * BN;

    float acc[8][8];
#pragma unroll
    for (int i = 0; i < 8; ++i)
#pragma unroll
        for (int j = 0; j < 8; ++j) acc[i][j] = 0.f;

    for (int k0 = 0; k0 < K; k0 += BK) {
#pragma unroll
        for (int l = tid; l < BM * BK; l += 256) {
            int kk = l & (BK - 1);
            int m  = l >> 4;
            int row = bm + m;
            float v = 0.f;
            if (row < M) v = loadf(A, (size_t)row * K + k0 + kk, aflag);
            As[kk][m] = v;
        }
#pragma unroll
        for (int l = tid; l < BK * BN; l += 256) {
            int n  = l & (BN - 1);
            int kk = l >> 7;
            Bs[kk][n] = B[(size_t)(k0 + kk) * Nn + bn + n];
        }
        __syncthreads();

#pragma unroll
        for (int kk = 0; kk < BK; ++kk) {
            float a[8], b[8];
#pragma unroll
            for (int i = 0; i < 8; ++i) a[i] = As[kk][ty * 8 + i];
#pragma unroll
            for (int j = 0; j < 8; ++j) b[j] = Bs[kk][tx * 8 + j];
#pragma unroll
            for (int i = 0; i < 8; ++i)
#pragma unroll
                for (int j = 0; j < 8; ++j) acc[i][j] += a[i] * b[j];
        }
        __syncthreads();
    }

#pragma unroll
    for (int i = 0; i < 8; ++i) {
        int row = bm + ty * 8 + i;
        if (row >= M) continue;
        size_t base = (size_t)row * Nn + bn + tx * 8;
#pragma unroll
        for (int j = 0; j < 8; ++j) store_out(C, base + j, acc[i][j]);
    }
}

// ---------------- attention scalar products (per node) ----------------

__global__ void alpha1_kernel(const __hip_bfloat16* __restrict__ h1,
                              const float* __restrict__ asw,
                              const float* __restrict__ adw,
                              float* __restrict__ as1, float* __restrict__ ad1,
                              int n) {
    int gt = blockIdx.x * blockDim.x + threadIdx.x;
    int v = gt >> 6;
    int lane = gt & 63;
    if (v >= n) return;
#pragma unroll
    for (int h = 0; h < HEADS; ++h) {
        float val = __bfloat162float(h1[(size_t)v * HID + h * C1 + lane]);
        float s = val * asw[h * C1 + lane];
        float d = val * adw[h * C1 + lane];
#pragma unroll
        for (int o = 32; o > 0; o >>= 1) {
            s += __shfl_down(s, o);
            d += __shfl_down(d, o);
        }
        if (lane == 0) {
            as1[v * HEADS + h] = s;
            ad1[v * HEADS + h] = d;
        }
    }
}

__global__ void alpha2_kernel(const float* __restrict__ h2,
                              const float* __restrict__ asw,
                              const float* __restrict__ adw,
                              float* __restrict__ as2, float* __restrict__ ad2,
                              int n) {
    int gt = blockIdx.x * blockDim.x + threadIdx.x;
    int v = gt >> 6;
    int lane = gt & 63;
    if (v >= n) return;
    float v0 = h2[(size_t)v * OUT_DIM + lane];
    float v1 = h2[(size_t)v * OUT_DIM + 64 + lane];
    float s = v0 * asw[lane] + v1 * asw[64 + lane];
    float d = v0 * adw[lane] + v1 * adw[64 + lane];
#pragma unroll
    for (int o = 32; o > 0; o >>= 1) {
        s += __shfl_down(s, o);
        d += __shfl_down(d, o);
    }
    if (lane == 0) { as2[v] = s; ad2[v] = d; }
}

// ---------------- edge softmax: normalized alpha per (edge, head) ---------

// wave per node; lane l: edge slot (l>>2), head (l&3).
__global__ __launch_bounds__(256) void attn1_kernel(
    const float* __restrict__ as1, const float* __restrict__ ad1,
    const int* __restrict__ offs, const int* __restrict__ ssrc,
    float* __restrict__ alpha, int n) {
    int v = blockIdx.x * 4 + (threadIdx.x >> 6);
    if (v >= n) return;
    int l = threadIdx.x & 63;
    int h = l & 3;
    int eoff = l >> 2;
    int start = offs[v], end = offs[v + 1];
    float adv = ad1[v * 4 + h];

    float m = -1e30f;
    for (int i = start + eoff; i < end; i += 16)
        m = fmaxf(m, leaky(as1[ssrc[i] * 4 + h] + adv));
#pragma unroll
    for (int o = 4; o < 64; o <<= 1) m = fmaxf(m, __shfl_xor(m, o));

    float den = 0.f;
    for (int i = start + eoff; i < end; i += 16) {
        float w = __expf(leaky(as1[ssrc[i] * 4 + h] + adv) - m);
        alpha[(size_t)i * 4 + h] = w;
        den += w;
    }
#pragma unroll
    for (int o = 4; o < 64; o <<= 1) den += __shfl_xor(den, o);
    float r = 1.f / (den + 1e-16f);

    for (int j = start * 4 + l; j < end * 4; j += 64) alpha[j] *= r;
}

// wave per node, single head.
__global__ __launch_bounds__(256) void attn2_kernel(
    const float* __restrict__ as2, const float* __restrict__ ad2,
    const int* __restrict__ offs, const int* __restrict__ ssrc,
    float* __restrict__ alpha, int n) {
    int v = blockIdx.x * 4 + (threadIdx.x >> 6);
    if (v >= n) return;
    int l = threadIdx.x & 63;
    int start = offs[v], end = offs[v + 1];
    float adv = ad2[v];

    float m = -1e30f;
    for (int i = start + l; i < end; i += 64)
        m = fmaxf(m, leaky(as2[ssrc[i]] + adv));
#pragma unroll
    for (int o = 1; o < 64; o <<= 1) m = fmaxf(m, __shfl_xor(m, o));

    float den = 0.f;
    for (int i = start + l; i < end; i += 64) {
        float w = __expf(leaky(as2[ssrc[i]] + adv) - m);
        alpha[i] = w;
        den += w;
    }
#pragma unroll
    for (int o = 1; o < 64; o <<= 1) den += __shfl_xor(den, o);
    float r = 1.f / (den + 1e-16f);

    for (int i = start + l; i < end; i += 64) alpha[i] *= r;
}

// ---------------- weighted-gather aggregation ----------------

// 128 threads per node (2 nodes/block); thread t = channels {2t, 2t+1}.
__global__ __launch_bounds__(256) void agg1v_kernel(
    const __hip_bfloat162* __restrict__ h1, const float* __restrict__ alpha,
    const int* __restrict__ offs, const int* __restrict__ ssrc,
    const float* __restrict__ bias1, __hip_bfloat162* __restrict__ g, int n) {
    int t = threadIdx.x & 127;
    int v = blockIdx.x * 2 + (threadIdx.x >> 7);
    if (v >= n) return;
    int head = t >> 5;                  // channel 2t -> head (2t)/64
    int start = offs[v], end = offs[v + 1];

    float nx = 0.f, ny = 0.f;
    for (int i = start; i < end; ++i) {
        int s = ssrc[i];
        float w = alpha[(size_t)i * 4 + head];
        __hip_bfloat162 hv = h1[s * 128 + t];
        nx += w * __bfloat162float(hv.x);
        ny += w * __bfloat162float(hv.y);
    }
    float ox = nx + bias1[2 * t];
    float oy = ny + bias1[2 * t + 1];
    ox = 0.5f * ox * (1.0f + erff(ox * 0.70710678118654752440f));
    oy = 0.5f * oy * (1.0f + erff(oy * 0.70710678118654752440f));
    __hip_bfloat162 r;
    r.x = __float2bfloat16(ox);
    r.y = __float2bfloat16(oy);
    g[(size_t)v * 128 + t] = r;
}

// 64 threads per node (4 nodes/block); thread t = channels {2t, 2t+1}.
__global__ __launch_bounds__(256) void agg2v_kernel(
    const float2* __restrict__ h2, const float* __restrict__ alpha,
    const int* __restrict__ offs, const int* __restrict__ ssrc,
    const float* __restrict__ bias2, void* __restrict__ out,
    const int* outflagp, int n) {
    int t = threadIdx.x & 63;
    int v = blockIdx.x * 4 + (threadIdx.x >> 6);
    if (v >= n) return;
    int start = offs[v], end = offs[v + 1];

    float nx = 0.f, ny = 0.f;
    for (int i = start; i < end; ++i) {
        int s = ssrc[i];
        float w = alpha[i];
        float2 hv = h2[s * 64 + t];
        nx += w * hv.x;
        ny += w * hv.y;
    }
    float ox = nx + bias2[2 * t];
    float oy = ny + bias2[2 * t + 1];
    size_t oi = (size_t)v * 64 + t;
    if (*outflagp) {
        __hip_bfloat162 r;
        r.x = __float2bfloat16(ox);
        r.y = __float2bfloat16(oy);
        ((__hip_bfloat162*)out)[oi] = r;
    } else {
        ((float2*)out)[oi] = make_float2(ox, oy);
    }
}

// ---------------------------------------------------------------------------

extern "C" void kernel_launch(void* const* d_in, const int* in_sizes, int n_in,
                              void* d_out, int out_size, void* d_ws, size_t ws_size,
                              hipStream_t stream) {
    const void* x    = d_in[0];
    const int*  ei   = (const int*)d_in[1];
    const void* W1   = d_in[2];
    const void* as1w = d_in[3];
    const void* ad1w = d_in[4];
    const void* b1   = d_in[5];
    const void* W2   = d_in[6];
    const void* as2w = d_in[7];
    const void* ad2w = d_in[8];
    const void* b2   = d_in[9];

    const int N  = out_size / OUT_DIM;       // 50000
    const int E  = in_sizes[1] / 2;          // 800000
    const int EP = E + N;

    // ---- workspace carve ----
    float* W1f   = (float*)d_ws;                       // 65536
    float* W2f   = W1f + IN_DIM * HID;                 // 32768
    float* as1wf = W2f + HID * OUT_DIM;                // 256
    float* ad1wf = as1wf + HEADS * C1;                 // 256
    float* b1f   = ad1wf + HEADS * C1;                 // 256
    float* as2wf = b1f + HID;                          // 128
    float* ad2wf = as2wf + OUT_DIM;                    // 128
    float* b2f   = ad2wf + OUT_DIM;                    // 128
    float* h2    = b2f + OUT_DIM;                      // N*128
    float* as1   = h2 + (size_t)N * OUT_DIM;           // N*4
    float* ad1   = as1 + (size_t)N * HEADS;            // N*4
    float* as2   = ad1 + (size_t)N * HEADS;            // N
    float* ad2   = as2 + (size_t)N;                    // N
    float* al1   = ad2 + (size_t)N;                    // EP*4 (normalized alpha L1)
    float* al2   = al1 + (size_t)EP * HEADS;           // EP
    int*   flags = (int*)(al2 + (size_t)EP);           // 16
    int*   deg    = flags + 16;                        // N
    int*   offs   = deg + N;                           // N+1
    int*   cursor = offs + N + 1;                      // N
    int*   ssrc   = cursor + N;                        // EP
    __hip_bfloat16* h1 = (__hip_bfloat16*)(ssrc + EP); // N*256
    __hip_bfloat16* g  = h1 + (size_t)N * HID;         // N*256

    // ---- dtype detection ----
    detect_kernel<<<1, 256, 0, stream>>>(x,    in_sizes[0], flags + 0);
    detect_kernel<<<1, 256, 0, stream>>>(W1,   in_sizes[2], flags + 1);
    detect_kernel<<<1, 256, 0, stream>>>(as1w, in_sizes[3], flags + 2);
    detect_kernel<<<1, 256, 0, stream>>>(ad1w, in_sizes[4], flags + 3);
    detect_kernel<<<1, 256, 0, stream>>>(b1,   in_sizes[5], flags + 4);
    detect_kernel<<<1, 256, 0, stream>>>(W2,   in_sizes[6], flags + 5);
    detect_kernel<<<1, 256, 0, stream>>>(as2w, in_sizes[7], flags + 6);
    detect_kernel<<<1, 256, 0, stream>>>(ad2w, in_sizes[8], flags + 7);
    detect_kernel<<<1, 256, 0, stream>>>(b2,   in_sizes[9], flags + 8);

    // ---- convert small tensors to fp32 ----
    cvt_kernel<<<(IN_DIM * HID + 255) / 256, 256, 0, stream>>>(W1, flags + 1, W1f, IN_DIM * HID);
    cvt_kernel<<<1, 256, 0, stream>>>(as1w, flags + 2, as1wf, HEADS * C1);
    cvt_kernel<<<1, 256, 0, stream>>>(ad1w, flags + 3, ad1wf, HEADS * C1);
    cvt_kernel<<<1, 256, 0, stream>>>(b1,   flags + 4, b1f,   HID);
    cvt_kernel<<<(HID * OUT_DIM + 255) / 256, 256, 0, stream>>>(W2, flags + 5, W2f, HID * OUT_DIM);
    cvt_kernel<<<1, 256, 0, stream>>>(as2w, flags + 6, as2wf, OUT_DIM);
    cvt_kernel<<<1, 256, 0, stream>>>(ad2w, flags + 7, ad2wf, OUT_DIM);
    cvt_kernel<<<1, 256, 0, stream>>>(b2,   flags + 8, b2f,   OUT_DIM);

    // ---- CSR build ----
    hipMemsetAsync(deg, 0, (size_t)N * sizeof(int), stream);
    {
        int blk = 256, grd = (EP + blk - 1) / blk;
        count_kernel<<<grd, blk, 0, stream>>>(ei, E, EP, deg);
        scan_kernel<<<1, 1024, 0, stream>>>(deg, offs, cursor, N);
        fill_kernel<<<grd, blk, 0, stream>>>(ei, E, EP, cursor, ssrc);
    }

    // ---- layer 1 ----
    {
        dim3 grd(HID / 128, (N + 127) / 128);
        gemm_kernel<__hip_bfloat16><<<grd, 256, 0, stream>>>(x, flags + 0, W1f, h1, N, HID, IN_DIM);
    }
    alpha1_kernel<<<((N * 64) + 255) / 256, 256, 0, stream>>>(h1, as1wf, ad1wf, as1, ad1, N);
    attn1_kernel<<<(N + 3) / 4, 256, 0, stream>>>(as1, ad1, offs, ssrc, al1, N);
    agg1v_kernel<<<(N + 1) / 2, 256, 0, stream>>>((const __hip_bfloat162*)h1, al1, offs, ssrc,
                                                  b1f, (__hip_bfloat162*)g, N);

    // ---- layer 2 ----
    {
        dim3 grd(OUT_DIM / 128, (N + 127) / 128);
        gemm_kernel<float><<<grd, 256, 0, stream>>>(g, nullptr, W2f, h2, N, OUT_DIM, HID);
    }
    alpha2_kernel<<<((N * 64) + 255) / 256, 256, 0, stream>>>(h2, as2wf, ad2wf, as2, ad2, N);
    attn2_kernel<<<(N + 3) / 4, 256, 0, stream>>>(as2, ad2, offs, ssrc, al2, N);
    agg2v_kernel<<<(N + 3) / 4, 256, 0, stream>>>((const float2*)h2, al2, offs, ssrc,
                                                  b2f, d_out, flags + 0, N);
}

// Round 5
// 676.266 us; speedup vs baseline: 1.4899x; 1.3228x over previous
//
#include <hip/hip_runtime.h>
#include <hip/hip_bf16.h>

// ---------------------------------------------------------------------------
// 2-layer GAT on MI355X (gfx950).
// R4b: MFMA GEMMs (mfma_f32_16x16x32_bf16, 128x128 tile, padded LDS) +
//      workspace slimmed to ~74 MB (h1/h2 union; deg doubles as fill cursor)
//      after R4's 100,001,344-byte carve crossed the (apparent) 1e8 ws limit.
// ---------------------------------------------------------------------------

#define IN_DIM   256
#define HID      256
#define HEADS    4
#define C1       64
#define OUT_DIM  128
#define NEG_SLOPE 0.2f

using short8 = __attribute__((ext_vector_type(8))) short;
using f32x4  = __attribute__((ext_vector_type(4))) float;

__device__ __forceinline__ float loadf(const void* p, size_t i, int isbf16) {
    return isbf16 ? __bfloat162float(((const __hip_bfloat16*)p)[i])
                  : ((const float*)p)[i];
}

__device__ __forceinline__ float leaky(float a) {
    return a > 0.f ? a : NEG_SLOPE * a;
}

__device__ __forceinline__ unsigned short f2bs(float f) {
    __hip_bfloat16 b = __float2bfloat16(f);
    return *reinterpret_cast<unsigned short*>(&b);
}

// ---------------- fused prep: detect dtype of 9 tensors + cvt small vecs ---

__global__ void prep_kernel(const void* x, int nx,
                            const void* W1, const void* as1w, const void* ad1w,
                            const void* b1, const void* W2, const void* as2w,
                            const void* ad2w, const void* b2,
                            float* as1wf, float* ad1wf, float* b1f,
                            float* as2wf, float* ad2wf, float* b2f,
                            int* flags) {
    const void* srcs[9] = {x, W1, as1w, ad1w, b1, W2, as2w, ad2w, b2};
    int ns[9] = {nx, IN_DIM * HID, HEADS * C1, HEADS * C1, HID,
                 HID * OUT_DIM, OUT_DIM, OUT_DIM, OUT_DIM};
    float* dsts[9] = {nullptr, nullptr, as1wf, ad1wf, b1f, nullptr, as2wf, ad2wf, b2f};

    int b = blockIdx.x;
    const unsigned short* u = (const unsigned short*)srcs[b];
    int n = ns[b];
    int nslots = n < 4096 ? n : 4096;
    int cnt = 0;
    for (int i = threadIdx.x; i < nslots; i += 256) {
        unsigned short a = u[i] & 0x7FFF;
        int e = a >> 7;
        if (a == 0 || (e >= 90 && e <= 140)) cnt++;
    }
    __shared__ int red[4];
    __shared__ int flagS;
    for (int o = 32; o > 0; o >>= 1) cnt += __shfl_down(cnt, o);
    if ((threadIdx.x & 63) == 0) red[threadIdx.x >> 6] = cnt;
    __syncthreads();
    if (threadIdx.x == 0) {
        int tot = red[0] + red[1] + red[2] + red[3];
        int f = (tot * 10 >= nslots * 8) ? 1 : 0;
        flags[b] = f;
        flagS = f;
    }
    __syncthreads();
    int f = flagS;
    float* d = dsts[b];
    if (d) {
        for (int i = threadIdx.x; i < n; i += 256) d[i] = loadf(srcs[b], i, f);
    }
}

// transpose W1 [256][256] -> W1T [n][k] bf16, W2 [256][128] -> W2T [n][k]
__global__ void tpose_kernel(const void* W1, const void* W2,
                             const int* flags,
                             __hip_bfloat16* __restrict__ W1T,
                             __hip_bfloat16* __restrict__ W2T) {
    int b = blockIdx.x;
    int t = threadIdx.x;
    if (b < 256) {            // W1: 65536 elems
        int i = b * 256 + t;
        int k = i >> 8, n = i & 255;
        W1T[n * 256 + k] = __float2bfloat16(loadf(W1, i, flags[1]));
    } else {                  // W2: 32768 elems
        int i = (b - 256) * 256 + t;
        int k = i >> 7, n = i & 127;
        W2T[n * 256 + k] = __float2bfloat16(loadf(W2, i, flags[5]));
    }
}

// ---------------- CSR build ----------------

__global__ void count_kernel(const int* __restrict__ ei, int E, int EP,
                             int* __restrict__ deg) {
    int idx = blockIdx.x * blockDim.x + threadIdx.x;
    if (idx >= EP) return;
    int d = (idx < E) ? ei[E + idx] : (idx - E);
    atomicAdd(&deg[d], 1);
}

// reads deg, writes offs; rewrites deg as the running cursor (deg reused).
__global__ void scan_kernel(int* __restrict__ deg, int* __restrict__ offs, int n) {
    __shared__ int partial[1024];
    int t = threadIdx.x;
    int chunk = (n + 1023) >> 10;
    int begin = t * chunk;
    int end   = begin + chunk; if (end > n) end = n;
    int s = 0;
    for (int i = begin; i < end; ++i) s += deg[i];
    partial[t] = s;
    __syncthreads();
    for (int d = 1; d < 1024; d <<= 1) {
        int v = (t >= d) ? partial[t - d] : 0;
        __syncthreads();
        partial[t] += v;
        __syncthreads();
    }
    int run = (t == 0) ? 0 : partial[t - 1];
    for (int i = begin; i < end; ++i) {
        int d = deg[i];          // read BEFORE clobbering
        offs[i] = run;
        deg[i]  = run;           // deg becomes fill cursor
        run += d;
    }
    if (t == 1023) offs[n] = partial[1023];
}

__global__ void fill_kernel(const int* __restrict__ ei, int E, int EP,
                            int* __restrict__ cursor, int* __restrict__ ssrc) {
    int idx = blockIdx.x * blockDim.x + threadIdx.x;
    if (idx >= EP) return;
    int src = (idx < E) ? ei[idx]     : (idx - E);
    int dst = (idx < E) ? ei[E + idx] : (idx - E);
    int pos = atomicAdd(&cursor[dst], 1);
    ssrc[pos] = src;
}

// ---------------- MFMA GEMM: C[M,Nn] = A[M,K](bf16|f32) @ BT[Nn,K]^T -------
// 256 threads = 4 waves in 2x2; wave tile 64x64 = 4x4 frags of 16x16.
// LDS rows padded to 40 bf16 (80 B) for conflict-light b128 access.

__device__ __forceinline__ void store_out(float* C, size_t i, float v) { C[i] = v; }
__device__ __forceinline__ void store_out(__hip_bfloat16* C, size_t i, float v) {
    C[i] = __float2bfloat16(v);
}

template <typename OutT>
__global__ __launch_bounds__(256) void gemm_mfma(
    const void* __restrict__ A0, const int* aflagp,
    const __hip_bfloat16* __restrict__ BT,
    OutT* __restrict__ C, int M, int Nn, int K) {
    constexpr int BM = 128, BN = 128, BK = 32;
    constexpr int LDK = BK + 8;   // 40 bf16 = 80 B row stride
    __shared__ __hip_bfloat16 As[BM * LDK];
    __shared__ __hip_bfloat16 Bs[BN * LDK];

    const int aflag = aflagp ? *aflagp : 1;
    const int tid  = threadIdx.x;
    const int lane = tid & 63;
    const int wv   = tid >> 6;
    const int wm   = (wv >> 1) * 64;
    const int wn   = (wv & 1) * 64;
    const int l15  = lane & 15;
    const int quad = lane >> 4;

    const int bm = blockIdx.y * BM;
    const int bn = blockIdx.x * BN;

    f32x4 acc[4][4] = {};

    for (int k0 = 0; k0 < K; k0 += BK) {
#pragma unroll
        for (int i = 0; i < 2; ++i) {
            int c    = tid + i * 256;      // 0..511
            int row  = c >> 2;             // 0..127
            int koff = (c & 3) * 8;
            int grow = bm + row;
            short8 av = {};
            if (grow < M) {
                if (aflag) {
                    av = *(const short8*)((const __hip_bfloat16*)A0 +
                                          (size_t)grow * K + k0 + koff);
                } else {
                    const float* ap = (const float*)A0 + (size_t)grow * K + k0 + koff;
                    float4 f0 = *(const float4*)ap;
                    float4 f1 = *(const float4*)(ap + 4);
                    av[0] = (short)f2bs(f0.x); av[1] = (short)f2bs(f0.y);
                    av[2] = (short)f2bs(f0.z); av[3] = (short)f2bs(f0.w);
                    av[4] = (short)f2bs(f1.x); av[5] = (short)f2bs(f1.y);
                    av[6] = (short)f2bs(f1.z); av[7] = (short)f2bs(f1.w);
                }
            }
            *(short8*)&As[row * LDK + koff] = av;
            short8 bv = *(const short8*)(BT + (size_t)(bn + row) * K + k0 + koff);
            *(short8*)&Bs[row * LDK + koff] = bv;
        }
        __syncthreads();

        short8 af[4], bf[4];
#pragma unroll
        for (int f = 0; f < 4; ++f) {
            af[f] = *(const short8*)&As[(wm + f * 16 + l15) * LDK + quad * 8];
            bf[f] = *(const short8*)&Bs[(wn + f * 16 + l15) * LDK + quad * 8];
        }
#pragma unroll
        for (int fm = 0; fm < 4; ++fm)
#pragma unroll
            for (int fn = 0; fn < 4; ++fn)
                acc[fm][fn] = __builtin_amdgcn_mfma_f32_16x16x32_bf16(
                    af[fm], bf[fn], acc[fm][fn], 0, 0, 0);
        __syncthreads();
    }

    // epilogue: C/D layout col=lane&15, row=quad*4+reg
#pragma unroll
    for (int fm = 0; fm < 4; ++fm) {
#pragma unroll
        for (int r = 0; r < 4; ++r) {
            int grow = bm + wm + fm * 16 + quad * 4 + r;
            if (grow >= M) continue;
#pragma unroll
            for (int fn = 0; fn < 4; ++fn) {
                int gcol = bn + wn + fn * 16 + l15;
                store_out(C, (size_t)grow * Nn + gcol, acc[fm][fn][r]);
            }
        }
    }
}

// ---------------- attention scalar products (per node) ----------------

__global__ void alpha1_kernel(const __hip_bfloat16* __restrict__ h1,
                              const float* __restrict__ asw,
                              const float* __restrict__ adw,
                              float* __restrict__ as1, float* __restrict__ ad1,
                              int n) {
    int gt = blockIdx.x * blockDim.x + threadIdx.x;
    int v = gt >> 6;
    int lane = gt & 63;
    if (v >= n) return;
#pragma unroll
    for (int h = 0; h < HEADS; ++h) {
        float val = __bfloat162float(h1[(size_t)v * HID + h * C1 + lane]);
        float s = val * asw[h * C1 + lane];
        float d = val * adw[h * C1 + lane];
#pragma unroll
        for (int o = 32; o > 0; o >>= 1) {
            s += __shfl_down(s, o);
            d += __shfl_down(d, o);
        }
        if (lane == 0) {
            as1[v * HEADS + h] = s;
            ad1[v * HEADS + h] = d;
        }
    }
}

__global__ void alpha2_kernel(const float* __restrict__ h2,
                              const float* __restrict__ asw,
                              const float* __restrict__ adw,
                              float* __restrict__ as2, float* __restrict__ ad2,
                              int n) {
    int gt = blockIdx.x * blockDim.x + threadIdx.x;
    int v = gt >> 6;
    int lane = gt & 63;
    if (v >= n) return;
    float v0 = h2[(size_t)v * OUT_DIM + lane];
    float v1 = h2[(size_t)v * OUT_DIM + 64 + lane];
    float s = v0 * asw[lane] + v1 * asw[64 + lane];
    float d = v0 * adw[lane] + v1 * adw[64 + lane];
#pragma unroll
    for (int o = 32; o > 0; o >>= 1) {
        s += __shfl_down(s, o);
        d += __shfl_down(d, o);
    }
    if (lane == 0) { as2[v] = s; ad2[v] = d; }
}

// ---------------- edge softmax: normalized alpha per (edge, head) ---------

__global__ __launch_bounds__(256) void attn1_kernel(
    const float* __restrict__ as1, const float* __restrict__ ad1,
    const int* __restrict__ offs, const int* __restrict__ ssrc,
    float* __restrict__ alpha, int n) {
    int v = blockIdx.x * 4 + (threadIdx.x >> 6);
    if (v >= n) return;
    int l = threadIdx.x & 63;
    int h = l & 3;
    int eoff = l >> 2;
    int start = offs[v], end = offs[v + 1];
    float adv = ad1[v * 4 + h];

    float m = -1e30f;
    for (int i = start + eoff; i < end; i += 16)
        m = fmaxf(m, leaky(as1[ssrc[i] * 4 + h] + adv));
#pragma unroll
    for (int o = 4; o < 64; o <<= 1) m = fmaxf(m, __shfl_xor(m, o));

    float den = 0.f;
    for (int i = start + eoff; i < end; i += 16) {
        float w = __expf(leaky(as1[ssrc[i] * 4 + h] + adv) - m);
        alpha[(size_t)i * 4 + h] = w;
        den += w;
    }
#pragma unroll
    for (int o = 4; o < 64; o <<= 1) den += __shfl_xor(den, o);
    float r = 1.f / (den + 1e-16f);

    for (int j = start * 4 + l; j < end * 4; j += 64) alpha[j] *= r;
}

__global__ __launch_bounds__(256) void attn2_kernel(
    const float* __restrict__ as2, const float* __restrict__ ad2,
    const int* __restrict__ offs, const int* __restrict__ ssrc,
    float* __restrict__ alpha, int n) {
    int v = blockIdx.x * 4 + (threadIdx.x >> 6);
    if (v >= n) return;
    int l = threadIdx.x & 63;
    int start = offs[v], end = offs[v + 1];
    float adv = ad2[v];

    float m = -1e30f;
    for (int i = start + l; i < end; i += 64)
        m = fmaxf(m, leaky(as2[ssrc[i]] + adv));
#pragma unroll
    for (int o = 1; o < 64; o <<= 1) m = fmaxf(m, __shfl_xor(m, o));

    float den = 0.f;
    for (int i = start + l; i < end; i += 64) {
        float w = __expf(leaky(as2[ssrc[i]] + adv) - m);
        alpha[i] = w;
        den += w;
    }
#pragma unroll
    for (int o = 1; o < 64; o <<= 1) den += __shfl_xor(den, o);
    float r = 1.f / (den + 1e-16f);

    for (int i = start + l; i < end; i += 64) alpha[i] *= r;
}

// ---------------- weighted-gather aggregation ----------------

__global__ __launch_bounds__(256) void agg1v_kernel(
    const __hip_bfloat162* __restrict__ h1, const float* __restrict__ alpha,
    const int* __restrict__ offs, const int* __restrict__ ssrc,
    const float* __restrict__ bias1, __hip_bfloat162* __restrict__ g, int n) {
    int t = threadIdx.x & 127;
    int v = blockIdx.x * 2 + (threadIdx.x >> 7);
    if (v >= n) return;
    int head = t >> 5;
    int start = offs[v], end = offs[v + 1];

    float nx = 0.f, ny = 0.f;
    for (int i = start; i < end; ++i) {
        int s = ssrc[i];
        float w = alpha[(size_t)i * 4 + head];
        __hip_bfloat162 hv = h1[s * 128 + t];
        nx += w * __bfloat162float(hv.x);
        ny += w * __bfloat162float(hv.y);
    }
    float ox = nx + bias1[2 * t];
    float oy = ny + bias1[2 * t + 1];
    ox = 0.5f * ox * (1.0f + erff(ox * 0.70710678118654752440f));
    oy = 0.5f * oy * (1.0f + erff(oy * 0.70710678118654752440f));
    __hip_bfloat162 r;
    r.x = __float2bfloat16(ox);
    r.y = __float2bfloat16(oy);
    g[(size_t)v * 128 + t] = r;
}

__global__ __launch_bounds__(256) void agg2v_kernel(
    const float2* __restrict__ h2, const float* __restrict__ alpha,
    const int* __restrict__ offs, const int* __restrict__ ssrc,
    const float* __restrict__ bias2, void* __restrict__ out,
    const int* outflagp, int n) {
    int t = threadIdx.x & 63;
    int v = blockIdx.x * 4 + (threadIdx.x >> 6);
    if (v >= n) return;
    int start = offs[v], end = offs[v + 1];

    float nx = 0.f, ny = 0.f;
    for (int i = start; i < end; ++i) {
        int s = ssrc[i];
        float w = alpha[i];
        float2 hv = h2[s * 64 + t];
        nx += w * hv.x;
        ny += w * hv.y;
    }
    float ox = nx + bias2[2 * t];
    float oy = ny + bias2[2 * t + 1];
    size_t oi = (size_t)v * 64 + t;
    if (*outflagp) {
        __hip_bfloat162 r;
        r.x = __float2bfloat16(ox);
        r.y = __float2bfloat16(oy);
        ((__hip_bfloat162*)out)[oi] = r;
    } else {
        ((float2*)out)[oi] = make_float2(ox, oy);
    }
}

// ---------------------------------------------------------------------------

static inline char* alignp(char* p, size_t a) {
    return (char*)(((uintptr_t)p + a - 1) & ~(uintptr_t)(a - 1));
}

extern "C" void kernel_launch(void* const* d_in, const int* in_sizes, int n_in,
                              void* d_out, int out_size, void* d_ws, size_t ws_size,
                              hipStream_t stream) {
    const void* x    = d_in[0];
    const int*  ei   = (const int*)d_in[1];
    const void* W1   = d_in[2];
    const void* as1w = d_in[3];
    const void* ad1w = d_in[4];
    const void* b1   = d_in[5];
    const void* W2   = d_in[6];
    const void* as2w = d_in[7];
    const void* ad2w = d_in[8];
    const void* b2   = d_in[9];

    const int N  = out_size / OUT_DIM;       // 50000
    const int E  = in_sizes[1] / 2;          // 800000
    const int EP = E + N;

    // ---- workspace carve (~74.2 MB total; h1/h2 share one 25.6 MB union) --
    char* p = (char*)d_ws;
    // union buffer: h1 (bf16 N*256, layer 1) then h2 (f32 N*128, layer 2)
    __hip_bfloat16* h1 = (__hip_bfloat16*)p;
    float*          h2 = (float*)p;           p += (size_t)N * HID * 2;  // == N*OUT_DIM*4
    __hip_bfloat16* g  = (__hip_bfloat16*)p;  p += (size_t)N * HID * 2;
    float* as1wf = (float*)p;                 p += 256 * 4;
    float* ad1wf = (float*)p;                 p += 256 * 4;
    float* b1f   = (float*)p;                 p += 256 * 4;
    float* as2wf = (float*)p;                 p += 128 * 4;
    float* ad2wf = (float*)p;                 p += 128 * 4;
    float* b2f   = (float*)p;                 p += 128 * 4;
    float* as1   = (float*)p;                 p += (size_t)N * HEADS * 4;
    float* ad1   = (float*)p;                 p += (size_t)N * HEADS * 4;
    float* as2   = (float*)p;                 p += (size_t)N * 4;
    float* ad2   = (float*)p;                 p += (size_t)N * 4;
    float* al1   = (float*)p;                 p += (size_t)EP * HEADS * 4;
    float* al2   = (float*)p;                 p += (size_t)EP * 4;
    int*   flags = (int*)p;                   p += 16 * 4;
    int*   deg   = (int*)p;                   p += (size_t)N * 4;   // doubles as cursor
    int*   offs  = (int*)p;                   p += (size_t)(N + 1) * 4;
    int*   ssrc  = (int*)p;                   p += (size_t)EP * 4;
    p = alignp(p, 64);
    __hip_bfloat16* W1T = (__hip_bfloat16*)p; p += (size_t)HID * IN_DIM * 2;
    __hip_bfloat16* W2T = (__hip_bfloat16*)p; p += (size_t)OUT_DIM * HID * 2;

    // ---- prep: detect + small cvts (1 launch), transpose weights (1) ----
    prep_kernel<<<9, 256, 0, stream>>>(x, in_sizes[0], W1, as1w, ad1w, b1,
                                       W2, as2w, ad2w, b2,
                                       as1wf, ad1wf, b1f, as2wf, ad2wf, b2f,
                                       flags);
    tpose_kernel<<<384, 256, 0, stream>>>(W1, W2, flags, W1T, W2T);

    // ---- CSR build ----
    hipMemsetAsync(deg, 0, (size_t)N * sizeof(int), stream);
    {
        int blk = 256, grd = (EP + blk - 1) / blk;
        count_kernel<<<grd, blk, 0, stream>>>(ei, E, EP, deg);
        scan_kernel<<<1, 1024, 0, stream>>>(deg, offs, N);
        fill_kernel<<<grd, blk, 0, stream>>>(ei, E, EP, deg, ssrc);
    }

    // ---- layer 1 ----
    gemm_mfma<__hip_bfloat16><<<dim3(HID / 128, (N + 127) / 128), 256, 0, stream>>>(
        x, flags + 0, W1T, h1, N, HID, IN_DIM);
    alpha1_kernel<<<((N * 64) + 255) / 256, 256, 0, stream>>>(h1, as1wf, ad1wf, as1, ad1, N);
    attn1_kernel<<<(N + 3) / 4, 256, 0, stream>>>(as1, ad1, offs, ssrc, al1, N);
    agg1v_kernel<<<(N + 1) / 2, 256, 0, stream>>>((const __hip_bfloat162*)h1, al1, offs, ssrc,
                                                  b1f, (__hip_bfloat162*)g, N);

    // ---- layer 2 (h2 reuses h1's buffer; h1 is dead after agg1v) ----
    gemm_mfma<float><<<dim3(OUT_DIM / 128, (N + 127) / 128), 256, 0, stream>>>(
        g, nullptr, W2T, h2, N, OUT_DIM, HID);
    alpha2_kernel<<<((N * 64) + 255) / 256, 256, 0, stream>>>(h2, as2wf, ad2wf, as2, ad2, N);
    attn2_kernel<<<(N + 3) / 4, 256, 0, stream>>>(as2, ad2, offs, ssrc, al2, N);
    agg2v_kernel<<<(N + 3) / 4, 256, 0, stream>>>((const float2*)h2, al2, offs, ssrc,
                                                  b2f, d_out, flags + 0, N);
}

// Round 6
// 565.671 us; speedup vs baseline: 1.7812x; 1.1955x over previous
//
#include <hip/hip_runtime.h>
#include <hip/hip_bf16.h>

// ---------------------------------------------------------------------------
// 2-layer GAT on MI355X (gfx950).
// R5: agg kernels rebuilt for memory-level parallelism — one wave per node,
//     8B vector gathers, edge loop unrolled x4 with batched independent loads
//     (the R5 profile showed agg1v latency-bound: VALU 22%, HBM 17%).
// ---------------------------------------------------------------------------

#define IN_DIM   256
#define HID      256
#define HEADS    4
#define C1       64
#define OUT_DIM  128
#define NEG_SLOPE 0.2f

using short8 = __attribute__((ext_vector_type(8))) short;
using f32x4  = __attribute__((ext_vector_type(4))) float;

__device__ __forceinline__ float loadf(const void* p, size_t i, int isbf16) {
    return isbf16 ? __bfloat162float(((const __hip_bfloat16*)p)[i])
                  : ((const float*)p)[i];
}

__device__ __forceinline__ float leaky(float a) {
    return a > 0.f ? a : NEG_SLOPE * a;
}

__device__ __forceinline__ unsigned short f2bs(float f) {
    __hip_bfloat16 b = __float2bfloat16(f);
    return *reinterpret_cast<unsigned short*>(&b);
}

__device__ __forceinline__ float bs2f(unsigned short u) {
    return __uint_as_float((unsigned)u << 16);
}

// ---------------- fused prep: detect dtype of 9 tensors + cvt small vecs ---

__global__ void prep_kernel(const void* x, int nx,
                            const void* W1, const void* as1w, const void* ad1w,
                            const void* b1, const void* W2, const void* as2w,
                            const void* ad2w, const void* b2,
                            float* as1wf, float* ad1wf, float* b1f,
                            float* as2wf, float* ad2wf, float* b2f,
                            int* flags) {
    const void* srcs[9] = {x, W1, as1w, ad1w, b1, W2, as2w, ad2w, b2};
    int ns[9] = {nx, IN_DIM * HID, HEADS * C1, HEADS * C1, HID,
                 HID * OUT_DIM, OUT_DIM, OUT_DIM, OUT_DIM};
    float* dsts[9] = {nullptr, nullptr, as1wf, ad1wf, b1f, nullptr, as2wf, ad2wf, b2f};

    int b = blockIdx.x;
    const unsigned short* u = (const unsigned short*)srcs[b];
    int n = ns[b];
    int nslots = n < 4096 ? n : 4096;
    int cnt = 0;
    for (int i = threadIdx.x; i < nslots; i += 256) {
        unsigned short a = u[i] & 0x7FFF;
        int e = a >> 7;
        if (a == 0 || (e >= 90 && e <= 140)) cnt++;
    }
    __shared__ int red[4];
    __shared__ int flagS;
    for (int o = 32; o > 0; o >>= 1) cnt += __shfl_down(cnt, o);
    if ((threadIdx.x & 63) == 0) red[threadIdx.x >> 6] = cnt;
    __syncthreads();
    if (threadIdx.x == 0) {
        int tot = red[0] + red[1] + red[2] + red[3];
        int f = (tot * 10 >= nslots * 8) ? 1 : 0;
        flags[b] = f;
        flagS = f;
    }
    __syncthreads();
    int f = flagS;
    float* d = dsts[b];
    if (d) {
        for (int i = threadIdx.x; i < n; i += 256) d[i] = loadf(srcs[b], i, f);
    }
}

// transpose W1 [256][256] -> W1T [n][k] bf16, W2 [256][128] -> W2T [n][k]
__global__ void tpose_kernel(const void* W1, const void* W2,
                             const int* flags,
                             __hip_bfloat16* __restrict__ W1T,
                             __hip_bfloat16* __restrict__ W2T) {
    int b = blockIdx.x;
    int t = threadIdx.x;
    if (b < 256) {            // W1: 65536 elems
        int i = b * 256 + t;
        int k = i >> 8, n = i & 255;
        W1T[n * 256 + k] = __float2bfloat16(loadf(W1, i, flags[1]));
    } else {                  // W2: 32768 elems
        int i = (b - 256) * 256 + t;
        int k = i >> 7, n = i & 127;
        W2T[n * 256 + k] = __float2bfloat16(loadf(W2, i, flags[5]));
    }
}

// ---------------- CSR build ----------------

__global__ void count_kernel(const int* __restrict__ ei, int E, int EP,
                             int* __restrict__ deg) {
    int idx = blockIdx.x * blockDim.x + threadIdx.x;
    if (idx >= EP) return;
    int d = (idx < E) ? ei[E + idx] : (idx - E);
    atomicAdd(&deg[d], 1);
}

// reads deg, writes offs; rewrites deg as the running cursor (deg reused).
__global__ void scan_kernel(int* __restrict__ deg, int* __restrict__ offs, int n) {
    __shared__ int partial[1024];
    int t = threadIdx.x;
    int chunk = (n + 1023) >> 10;
    int begin = t * chunk;
    int end   = begin + chunk; if (end > n) end = n;
    int s = 0;
    for (int i = begin; i < end; ++i) s += deg[i];
    partial[t] = s;
    __syncthreads();
    for (int d = 1; d < 1024; d <<= 1) {
        int v = (t >= d) ? partial[t - d] : 0;
        __syncthreads();
        partial[t] += v;
        __syncthreads();
    }
    int run = (t == 0) ? 0 : partial[t - 1];
    for (int i = begin; i < end; ++i) {
        int d = deg[i];
        offs[i] = run;
        deg[i]  = run;
        run += d;
    }
    if (t == 1023) offs[n] = partial[1023];
}

__global__ void fill_kernel(const int* __restrict__ ei, int E, int EP,
                            int* __restrict__ cursor, int* __restrict__ ssrc) {
    int idx = blockIdx.x * blockDim.x + threadIdx.x;
    if (idx >= EP) return;
    int src = (idx < E) ? ei[idx]     : (idx - E);
    int dst = (idx < E) ? ei[E + idx] : (idx - E);
    int pos = atomicAdd(&cursor[dst], 1);
    ssrc[pos] = src;
}

// ---------------- MFMA GEMM: C[M,Nn] = A[M,K](bf16|f32) @ BT[Nn,K]^T -------

__device__ __forceinline__ void store_out(float* C, size_t i, float v) { C[i] = v; }
__device__ __forceinline__ void store_out(__hip_bfloat16* C, size_t i, float v) {
    C[i] = __float2bfloat16(v);
}

template <typename OutT>
__global__ __launch_bounds__(256) void gemm_mfma(
    const void* __restrict__ A0, const int* aflagp,
    const __hip_bfloat16* __restrict__ BT,
    OutT* __restrict__ C, int M, int Nn, int K) {
    constexpr int BM = 128, BN = 128, BK = 32;
    constexpr int LDK = BK + 8;
    __shared__ __hip_bfloat16 As[BM * LDK];
    __shared__ __hip_bfloat16 Bs[BN * LDK];

    const int aflag = aflagp ? *aflagp : 1;
    const int tid  = threadIdx.x;
    const int lane = tid & 63;
    const int wv   = tid >> 6;
    const int wm   = (wv >> 1) * 64;
    const int wn   = (wv & 1) * 64;
    const int l15  = lane & 15;
    const int quad = lane >> 4;

    const int bm = blockIdx.y * BM;
    const int bn = blockIdx.x * BN;

    f32x4 acc[4][4] = {};

    for (int k0 = 0; k0 < K; k0 += BK) {
#pragma unroll
        for (int i = 0; i < 2; ++i) {
            int c    = tid + i * 256;
            int row  = c >> 2;
            int koff = (c & 3) * 8;
            int grow = bm + row;
            short8 av = {};
            if (grow < M) {
                if (aflag) {
                    av = *(const short8*)((const __hip_bfloat16*)A0 +
                                          (size_t)grow * K + k0 + koff);
                } else {
                    const float* ap = (const float*)A0 + (size_t)grow * K + k0 + koff;
                    float4 f0 = *(const float4*)ap;
                    float4 f1 = *(const float4*)(ap + 4);
                    av[0] = (short)f2bs(f0.x); av[1] = (short)f2bs(f0.y);
                    av[2] = (short)f2bs(f0.z); av[3] = (short)f2bs(f0.w);
                    av[4] = (short)f2bs(f1.x); av[5] = (short)f2bs(f1.y);
                    av[6] = (short)f2bs(f1.z); av[7] = (short)f2bs(f1.w);
                }
            }
            *(short8*)&As[row * LDK + koff] = av;
            short8 bv = *(const short8*)(BT + (size_t)(bn + row) * K + k0 + koff);
            *(short8*)&Bs[row * LDK + koff] = bv;
        }
        __syncthreads();

        short8 af[4], bf[4];
#pragma unroll
        for (int f = 0; f < 4; ++f) {
            af[f] = *(const short8*)&As[(wm + f * 16 + l15) * LDK + quad * 8];
            bf[f] = *(const short8*)&Bs[(wn + f * 16 + l15) * LDK + quad * 8];
        }
#pragma unroll
        for (int fm = 0; fm < 4; ++fm)
#pragma unroll
            for (int fn = 0; fn < 4; ++fn)
                acc[fm][fn] = __builtin_amdgcn_mfma_f32_16x16x32_bf16(
                    af[fm], bf[fn], acc[fm][fn], 0, 0, 0);
        __syncthreads();
    }

#pragma unroll
    for (int fm = 0; fm < 4; ++fm) {
#pragma unroll
        for (int r = 0; r < 4; ++r) {
            int grow = bm + wm + fm * 16 + quad * 4 + r;
            if (grow >= M) continue;
#pragma unroll
            for (int fn = 0; fn < 4; ++fn) {
                int gcol = bn + wn + fn * 16 + l15;
                store_out(C, (size_t)grow * Nn + gcol, acc[fm][fn][r]);
            }
        }
    }
}

// ---------------- attention scalar products (per node) ----------------

__global__ void alpha1_kernel(const __hip_bfloat16* __restrict__ h1,
                              const float* __restrict__ asw,
                              const float* __restrict__ adw,
                              float* __restrict__ as1, float* __restrict__ ad1,
                              int n) {
    int gt = blockIdx.x * blockDim.x + threadIdx.x;
    int v = gt >> 6;
    int lane = gt & 63;
    if (v >= n) return;
#pragma unroll
    for (int h = 0; h < HEADS; ++h) {
        float val = __bfloat162float(h1[(size_t)v * HID + h * C1 + lane]);
        float s = val * asw[h * C1 + lane];
        float d = val * adw[h * C1 + lane];
#pragma unroll
        for (int o = 32; o > 0; o >>= 1) {
            s += __shfl_down(s, o);
            d += __shfl_down(d, o);
        }
        if (lane == 0) {
            as1[v * HEADS + h] = s;
            ad1[v * HEADS + h] = d;
        }
    }
}

__global__ void alpha2_kernel(const float* __restrict__ h2,
                              const float* __restrict__ asw,
                              const float* __restrict__ adw,
                              float* __restrict__ as2, float* __restrict__ ad2,
                              int n) {
    int gt = blockIdx.x * blockDim.x + threadIdx.x;
    int v = gt >> 6;
    int lane = gt & 63;
    if (v >= n) return;
    float v0 = h2[(size_t)v * OUT_DIM + lane];
    float v1 = h2[(size_t)v * OUT_DIM + 64 + lane];
    float s = v0 * asw[lane] + v1 * asw[64 + lane];
    float d = v0 * adw[lane] + v1 * adw[64 + lane];
#pragma unroll
    for (int o = 32; o > 0; o >>= 1) {
        s += __shfl_down(s, o);
        d += __shfl_down(d, o);
    }
    if (lane == 0) { as2[v] = s; ad2[v] = d; }
}

// ---------------- edge softmax: normalized alpha per (edge, head) ---------

__global__ __launch_bounds__(256) void attn1_kernel(
    const float* __restrict__ as1, const float* __restrict__ ad1,
    const int* __restrict__ offs, const int* __restrict__ ssrc,
    float* __restrict__ alpha, int n) {
    int v = blockIdx.x * 4 + (threadIdx.x >> 6);
    if (v >= n) return;
    int l = threadIdx.x & 63;
    int h = l & 3;
    int eoff = l >> 2;
    int start = offs[v], end = offs[v + 1];
    float adv = ad1[v * 4 + h];

    float m = -1e30f;
    for (int i = start + eoff; i < end; i += 16)
        m = fmaxf(m, leaky(as1[ssrc[i] * 4 + h] + adv));
#pragma unroll
    for (int o = 4; o < 64; o <<= 1) m = fmaxf(m, __shfl_xor(m, o));

    float den = 0.f;
    for (int i = start + eoff; i < end; i += 16) {
        float w = __expf(leaky(as1[ssrc[i] * 4 + h] + adv) - m);
        alpha[(size_t)i * 4 + h] = w;
        den += w;
    }
#pragma unroll
    for (int o = 4; o < 64; o <<= 1) den += __shfl_xor(den, o);
    float r = 1.f / (den + 1e-16f);

    for (int j = start * 4 + l; j < end * 4; j += 64) alpha[j] *= r;
}

__global__ __launch_bounds__(256) void attn2_kernel(
    const float* __restrict__ as2, const float* __restrict__ ad2,
    const int* __restrict__ offs, const int* __restrict__ ssrc,
    float* __restrict__ alpha, int n) {
    int v = blockIdx.x * 4 + (threadIdx.x >> 6);
    if (v >= n) return;
    int l = threadIdx.x & 63;
    int start = offs[v], end = offs[v + 1];
    float adv = ad2[v];

    float m = -1e30f;
    for (int i = start + l; i < end; i += 64)
        m = fmaxf(m, leaky(as2[ssrc[i]] + adv));
#pragma unroll
    for (int o = 1; o < 64; o <<= 1) m = fmaxf(m, __shfl_xor(m, o));

    float den = 0.f;
    for (int i = start + l; i < end; i += 64) {
        float w = __expf(leaky(as2[ssrc[i]] + adv) - m);
        alpha[i] = w;
        den += w;
    }
#pragma unroll
    for (int o = 1; o < 64; o <<= 1) den += __shfl_xor(den, o);
    float r = 1.f / (den + 1e-16f);

    for (int i = start + l; i < end; i += 64) alpha[i] *= r;
}

// ---------------- weighted-gather aggregation (MLP-optimized) --------------

// Layer 1: one WAVE per node; thread t = channels {4t..4t+3} (ushort4 = 8B).
// Edge loop unrolled x4: 4 independent gathers in flight per thread.
__global__ __launch_bounds__(256) void agg1v_kernel(
    const ushort4* __restrict__ h1, const float* __restrict__ alpha,
    const int* __restrict__ offs, const int* __restrict__ ssrc,
    const float* __restrict__ bias1, ushort4* __restrict__ g, int n) {
    int t = threadIdx.x & 63;
    int v = blockIdx.x * 4 + (threadIdx.x >> 6);
    if (v >= n) return;
    int head = t >> 4;                 // channel 4t -> head (4t)/64
    int start = offs[v], end = offs[v + 1];

    float a0 = 0.f, a1 = 0.f, a2 = 0.f, a3 = 0.f;
    int i = start;
    for (; i + 4 <= end; i += 4) {
        int s0 = ssrc[i], s1 = ssrc[i + 1], s2 = ssrc[i + 2], s3 = ssrc[i + 3];
        float w0 = alpha[(size_t)i * 4 + head];
        float w1 = alpha[(size_t)(i + 1) * 4 + head];
        float w2 = alpha[(size_t)(i + 2) * 4 + head];
        float w3 = alpha[(size_t)(i + 3) * 4 + head];
        ushort4 p0 = h1[(size_t)s0 * 64 + t];
        ushort4 p1 = h1[(size_t)s1 * 64 + t];
        ushort4 p2 = h1[(size_t)s2 * 64 + t];
        ushort4 p3 = h1[(size_t)s3 * 64 + t];
        a0 += w0 * bs2f(p0.x) + w1 * bs2f(p1.x) + w2 * bs2f(p2.x) + w3 * bs2f(p3.x);
        a1 += w0 * bs2f(p0.y) + w1 * bs2f(p1.y) + w2 * bs2f(p2.y) + w3 * bs2f(p3.y);
        a2 += w0 * bs2f(p0.z) + w1 * bs2f(p1.z) + w2 * bs2f(p2.z) + w3 * bs2f(p3.z);
        a3 += w0 * bs2f(p0.w) + w1 * bs2f(p1.w) + w2 * bs2f(p2.w) + w3 * bs2f(p3.w);
    }
    for (; i < end; ++i) {
        int s = ssrc[i];
        float w = alpha[(size_t)i * 4 + head];
        ushort4 p = h1[(size_t)s * 64 + t];
        a0 += w * bs2f(p.x);
        a1 += w * bs2f(p.y);
        a2 += w * bs2f(p.z);
        a3 += w * bs2f(p.w);
    }
    float4 bq = *(const float4*)&bias1[4 * t];
    float o0 = a0 + bq.x, o1 = a1 + bq.y, o2 = a2 + bq.z, o3 = a3 + bq.w;
    o0 = 0.5f * o0 * (1.0f + erff(o0 * 0.70710678f));
    o1 = 0.5f * o1 * (1.0f + erff(o1 * 0.70710678f));
    o2 = 0.5f * o2 * (1.0f + erff(o2 * 0.70710678f));
    o3 = 0.5f * o3 * (1.0f + erff(o3 * 0.70710678f));
    ushort4 r;
    r.x = f2bs(o0); r.y = f2bs(o1); r.z = f2bs(o2); r.w = f2bs(o3);
    g[(size_t)v * 64 + t] = r;
}

// Layer 2: one wave per node; thread t = channels {2t, 2t+1} (float2 = 8B).
__global__ __launch_bounds__(256) void agg2v_kernel(
    const float2* __restrict__ h2, const float* __restrict__ alpha,
    const int* __restrict__ offs, const int* __restrict__ ssrc,
    const float* __restrict__ bias2, void* __restrict__ out,
    const int* outflagp, int n) {
    int t = threadIdx.x & 63;
    int v = blockIdx.x * 4 + (threadIdx.x >> 6);
    if (v >= n) return;
    int start = offs[v], end = offs[v + 1];

    float nx = 0.f, ny = 0.f;
    int i = start;
    for (; i + 4 <= end; i += 4) {
        int s0 = ssrc[i], s1 = ssrc[i + 1], s2 = ssrc[i + 2], s3 = ssrc[i + 3];
        float w0 = alpha[i], w1 = alpha[i + 1], w2 = alpha[i + 2], w3 = alpha[i + 3];
        float2 p0 = h2[(size_t)s0 * 64 + t];
        float2 p1 = h2[(size_t)s1 * 64 + t];
        float2 p2 = h2[(size_t)s2 * 64 + t];
        float2 p3 = h2[(size_t)s3 * 64 + t];
        nx += w0 * p0.x + w1 * p1.x + w2 * p2.x + w3 * p3.x;
        ny += w0 * p0.y + w1 * p1.y + w2 * p2.y + w3 * p3.y;
    }
    for (; i < end; ++i) {
        int s = ssrc[i];
        float w = alpha[i];
        float2 p = h2[(size_t)s * 64 + t];
        nx += w * p.x;
        ny += w * p.y;
    }
    float ox = nx + bias2[2 * t];
    float oy = ny + bias2[2 * t + 1];
    size_t oi = (size_t)v * 64 + t;
    if (*outflagp) {
        __hip_bfloat162 r;
        r.x = __float2bfloat16(ox);
        r.y = __float2bfloat16(oy);
        ((__hip_bfloat162*)out)[oi] = r;
    } else {
        ((float2*)out)[oi] = make_float2(ox, oy);
    }
}

// ---------------------------------------------------------------------------

static inline char* alignp(char* p, size_t a) {
    return (char*)(((uintptr_t)p + a - 1) & ~(uintptr_t)(a - 1));
}

extern "C" void kernel_launch(void* const* d_in, const int* in_sizes, int n_in,
                              void* d_out, int out_size, void* d_ws, size_t ws_size,
                              hipStream_t stream) {
    const void* x    = d_in[0];
    const int*  ei   = (const int*)d_in[1];
    const void* W1   = d_in[2];
    const void* as1w = d_in[3];
    const void* ad1w = d_in[4];
    const void* b1   = d_in[5];
    const void* W2   = d_in[6];
    const void* as2w = d_in[7];
    const void* ad2w = d_in[8];
    const void* b2   = d_in[9];

    const int N  = out_size / OUT_DIM;       // 50000
    const int E  = in_sizes[1] / 2;          // 800000
    const int EP = E + N;

    // ---- workspace carve (~74.2 MB; h1/h2 union) ----
    char* p = (char*)d_ws;
    __hip_bfloat16* h1 = (__hip_bfloat16*)p;
    float*          h2 = (float*)p;           p += (size_t)N * HID * 2;
    __hip_bfloat16* g  = (__hip_bfloat16*)p;  p += (size_t)N * HID * 2;
    float* as1wf = (float*)p;                 p += 256 * 4;
    float* ad1wf = (float*)p;                 p += 256 * 4;
    float* b1f   = (float*)p;                 p += 256 * 4;
    float* as2wf = (float*)p;                 p += 128 * 4;
    float* ad2wf = (float*)p;                 p += 128 * 4;
    float* b2f   = (float*)p;                 p += 128 * 4;
    float* as1   = (float*)p;                 p += (size_t)N * HEADS * 4;
    float* ad1   = (float*)p;                 p += (size_t)N * HEADS * 4;
    float* as2   = (float*)p;                 p += (size_t)N * 4;
    float* ad2   = (float*)p;                 p += (size_t)N * 4;
    float* al1   = (float*)p;                 p += (size_t)EP * HEADS * 4;
    float* al2   = (float*)p;                 p += (size_t)EP * 4;
    int*   flags = (int*)p;                   p += 16 * 4;
    int*   deg   = (int*)p;                   p += (size_t)N * 4;
    int*   offs  = (int*)p;                   p += (size_t)(N + 1) * 4;
    int*   ssrc  = (int*)p;                   p += (size_t)EP * 4;
    p = alignp(p, 64);
    __hip_bfloat16* W1T = (__hip_bfloat16*)p; p += (size_t)HID * IN_DIM * 2;
    __hip_bfloat16* W2T = (__hip_bfloat16*)p; p += (size_t)OUT_DIM * HID * 2;

    // ---- prep ----
    prep_kernel<<<9, 256, 0, stream>>>(x, in_sizes[0], W1, as1w, ad1w, b1,
                                       W2, as2w, ad2w, b2,
                                       as1wf, ad1wf, b1f, as2wf, ad2wf, b2f,
                                       flags);
    tpose_kernel<<<384, 256, 0, stream>>>(W1, W2, flags, W1T, W2T);

    // ---- CSR build ----
    hipMemsetAsync(deg, 0, (size_t)N * sizeof(int), stream);
    {
        int blk = 256, grd = (EP + blk - 1) / blk;
        count_kernel<<<grd, blk, 0, stream>>>(ei, E, EP, deg);
        scan_kernel<<<1, 1024, 0, stream>>>(deg, offs, N);
        fill_kernel<<<grd, blk, 0, stream>>>(ei, E, EP, deg, ssrc);
    }

    // ---- layer 1 ----
    gemm_mfma<__hip_bfloat16><<<dim3(HID / 128, (N + 127) / 128), 256, 0, stream>>>(
        x, flags + 0, W1T, h1, N, HID, IN_DIM);
    alpha1_kernel<<<((N * 64) + 255) / 256, 256, 0, stream>>>(h1, as1wf, ad1wf, as1, ad1, N);
    attn1_kernel<<<(N + 3) / 4, 256, 0, stream>>>(as1, ad1, offs, ssrc, al1, N);
    agg1v_kernel<<<(N + 3) / 4, 256, 0, stream>>>((const ushort4*)h1, al1, offs, ssrc,
                                                  b1f, (ushort4*)g, N);

    // ---- layer 2 (h2 reuses h1's buffer) ----
    gemm_mfma<float><<<dim3(OUT_DIM / 128, (N + 127) / 128), 256, 0, stream>>>(
        g, nullptr, W2T, h2, N, OUT_DIM, HID);
    alpha2_kernel<<<((N * 64) + 255) / 256, 256, 0, stream>>>(h2, as2wf, ad2wf, as2, ad2, N);
    attn2_kernel<<<(N + 3) / 4, 256, 0, stream>>>(as2, ad2, offs, ssrc, al2, N);
    agg2v_kernel<<<(N + 3) / 4, 256, 0, stream>>>((const float2*)h2, al2, offs, ssrc,
                                                  b2f, d_out, flags + 0, N);
}

// Round 7
// 447.823 us; speedup vs baseline: 2.2499x; 1.2632x over previous
//
#include <hip/hip_runtime.h>
#include <hip/hip_bf16.h>

// ---------------------------------------------------------------------------
// 2-layer GAT on MI355X (gfx950).
// R6: single-block scan (111 us, 0.1% occupancy) replaced by 3-phase
//     multi-block scan (psum -> bscan -> wscan), each phase device-wide.
// ---------------------------------------------------------------------------

#define IN_DIM   256
#define HID      256
#define HEADS    4
#define C1       64
#define OUT_DIM  128
#define NEG_SLOPE 0.2f

using short8 = __attribute__((ext_vector_type(8))) short;
using f32x4  = __attribute__((ext_vector_type(4))) float;

__device__ __forceinline__ float loadf(const void* p, size_t i, int isbf16) {
    return isbf16 ? __bfloat162float(((const __hip_bfloat16*)p)[i])
                  : ((const float*)p)[i];
}

__device__ __forceinline__ float leaky(float a) {
    return a > 0.f ? a : NEG_SLOPE * a;
}

__device__ __forceinline__ unsigned short f2bs(float f) {
    __hip_bfloat16 b = __float2bfloat16(f);
    return *reinterpret_cast<unsigned short*>(&b);
}

__device__ __forceinline__ float bs2f(unsigned short u) {
    return __uint_as_float((unsigned)u << 16);
}

// ---------------- fused prep: detect dtype of 9 tensors + cvt small vecs ---

__global__ void prep_kernel(const void* x, int nx,
                            const void* W1, const void* as1w, const void* ad1w,
                            const void* b1, const void* W2, const void* as2w,
                            const void* ad2w, const void* b2,
                            float* as1wf, float* ad1wf, float* b1f,
                            float* as2wf, float* ad2wf, float* b2f,
                            int* flags) {
    const void* srcs[9] = {x, W1, as1w, ad1w, b1, W2, as2w, ad2w, b2};
    int ns[9] = {nx, IN_DIM * HID, HEADS * C1, HEADS * C1, HID,
                 HID * OUT_DIM, OUT_DIM, OUT_DIM, OUT_DIM};
    float* dsts[9] = {nullptr, nullptr, as1wf, ad1wf, b1f, nullptr, as2wf, ad2wf, b2f};

    int b = blockIdx.x;
    const unsigned short* u = (const unsigned short*)srcs[b];
    int n = ns[b];
    int nslots = n < 4096 ? n : 4096;
    int cnt = 0;
    for (int i = threadIdx.x; i < nslots; i += 256) {
        unsigned short a = u[i] & 0x7FFF;
        int e = a >> 7;
        if (a == 0 || (e >= 90 && e <= 140)) cnt++;
    }
    __shared__ int red[4];
    __shared__ int flagS;
    for (int o = 32; o > 0; o >>= 1) cnt += __shfl_down(cnt, o);
    if ((threadIdx.x & 63) == 0) red[threadIdx.x >> 6] = cnt;
    __syncthreads();
    if (threadIdx.x == 0) {
        int tot = red[0] + red[1] + red[2] + red[3];
        int f = (tot * 10 >= nslots * 8) ? 1 : 0;
        flags[b] = f;
        flagS = f;
    }
    __syncthreads();
    int f = flagS;
    float* d = dsts[b];
    if (d) {
        for (int i = threadIdx.x; i < n; i += 256) d[i] = loadf(srcs[b], i, f);
    }
}

// transpose W1 [256][256] -> W1T [n][k] bf16, W2 [256][128] -> W2T [n][k]
__global__ void tpose_kernel(const void* W1, const void* W2,
                             const int* flags,
                             __hip_bfloat16* __restrict__ W1T,
                             __hip_bfloat16* __restrict__ W2T) {
    int b = blockIdx.x;
    int t = threadIdx.x;
    if (b < 256) {
        int i = b * 256 + t;
        int k = i >> 8, n = i & 255;
        W1T[n * 256 + k] = __float2bfloat16(loadf(W1, i, flags[1]));
    } else {
        int i = (b - 256) * 256 + t;
        int k = i >> 7, n = i & 127;
        W2T[n * 256 + k] = __float2bfloat16(loadf(W2, i, flags[5]));
    }
}

// ---------------- CSR build ----------------

__global__ void count_kernel(const int* __restrict__ ei, int E, int EP,
                             int* __restrict__ deg) {
    int idx = blockIdx.x * blockDim.x + threadIdx.x;
    if (idx >= EP) return;
    int d = (idx < E) ? ei[E + idx] : (idx - E);
    atomicAdd(&deg[d], 1);
}

// --- 3-phase multi-block exclusive scan over deg[0..n) ---
// phase 1: per-block (256-elem chunk) sums
__global__ __launch_bounds__(256) void psum_kernel(const int* __restrict__ deg,
                                                   int* __restrict__ bsum, int n) {
    int i = blockIdx.x * 256 + threadIdx.x;
    int v = (i < n) ? deg[i] : 0;
#pragma unroll
    for (int o = 32; o > 0; o >>= 1) v += __shfl_down(v, o);
    __shared__ int red[4];
    if ((threadIdx.x & 63) == 0) red[threadIdx.x >> 6] = v;
    __syncthreads();
    if (threadIdx.x == 0) bsum[blockIdx.x] = red[0] + red[1] + red[2] + red[3];
}

// phase 2: exclusive scan of nb (<=1024) block sums, one block of 1024
__global__ __launch_bounds__(1024) void bscan_kernel(int* __restrict__ bsum, int nb) {
    __shared__ int sh[1024];
    int t = threadIdx.x;
    int v = (t < nb) ? bsum[t] : 0;
    sh[t] = v;
    __syncthreads();
    for (int d = 1; d < 1024; d <<= 1) {
        int u = (t >= d) ? sh[t - d] : 0;
        __syncthreads();
        sh[t] += u;
        __syncthreads();
    }
    if (t < nb) bsum[t] = sh[t] - v;   // exclusive prefix
}

// phase 3: intra-block scan + block offset -> offs; deg becomes fill cursor
__global__ __launch_bounds__(256) void wscan_kernel(int* __restrict__ deg,
                                                    const int* __restrict__ bsum,
                                                    int* __restrict__ offs, int n) {
    __shared__ int sh[256];
    int b = blockIdx.x;
    int i = b * 256 + threadIdx.x;
    int v = (i < n) ? deg[i] : 0;
    sh[threadIdx.x] = v;
    __syncthreads();
    for (int d = 1; d < 256; d <<= 1) {
        int u = (threadIdx.x >= d) ? sh[threadIdx.x - d] : 0;
        __syncthreads();
        sh[threadIdx.x] += u;
        __syncthreads();
    }
    int excl = sh[threadIdx.x] - v + bsum[b];
    if (i < n) {
        offs[i] = excl;
        deg[i]  = excl;          // cursor for fill
        if (i == n - 1) offs[n] = excl + v;
    }
}

__global__ void fill_kernel(const int* __restrict__ ei, int E, int EP,
                            int* __restrict__ cursor, int* __restrict__ ssrc) {
    int idx = blockIdx.x * blockDim.x + threadIdx.x;
    if (idx >= EP) return;
    int src = (idx < E) ? ei[idx]     : (idx - E);
    int dst = (idx < E) ? ei[E + idx] : (idx - E);
    int pos = atomicAdd(&cursor[dst], 1);
    ssrc[pos] = src;
}

// ---------------- MFMA GEMM: C[M,Nn] = A[M,K](bf16|f32) @ BT[Nn,K]^T -------

__device__ __forceinline__ void store_out(float* C, size_t i, float v) { C[i] = v; }
__device__ __forceinline__ void store_out(__hip_bfloat16* C, size_t i, float v) {
    C[i] = __float2bfloat16(v);
}

template <typename OutT>
__global__ __launch_bounds__(256) void gemm_mfma(
    const void* __restrict__ A0, const int* aflagp,
    const __hip_bfloat16* __restrict__ BT,
    OutT* __restrict__ C, int M, int Nn, int K) {
    constexpr int BM = 128, BN = 128, BK = 32;
    constexpr int LDK = BK + 8;
    __shared__ __hip_bfloat16 As[BM * LDK];
    __shared__ __hip_bfloat16 Bs[BN * LDK];

    const int aflag = aflagp ? *aflagp : 1;
    const int tid  = threadIdx.x;
    const int lane = tid & 63;
    const int wv   = tid >> 6;
    const int wm   = (wv >> 1) * 64;
    const int wn   = (wv & 1) * 64;
    const int l15  = lane & 15;
    const int quad = lane >> 4;

    const int bm = blockIdx.y * BM;
    const int bn = blockIdx.x * BN;

    f32x4 acc[4][4] = {};

    for (int k0 = 0; k0 < K; k0 += BK) {
#pragma unroll
        for (int i = 0; i < 2; ++i) {
            int c    = tid + i * 256;
            int row  = c >> 2;
            int koff = (c & 3) * 8;
            int grow = bm + row;
            short8 av = {};
            if (grow < M) {
                if (aflag) {
                    av = *(const short8*)((const __hip_bfloat16*)A0 +
                                          (size_t)grow * K + k0 + koff);
                } else {
                    const float* ap = (const float*)A0 + (size_t)grow * K + k0 + koff;
                    float4 f0 = *(const float4*)ap;
                    float4 f1 = *(const float4*)(ap + 4);
                    av[0] = (short)f2bs(f0.x); av[1] = (short)f2bs(f0.y);
                    av[2] = (short)f2bs(f0.z); av[3] = (short)f2bs(f0.w);
                    av[4] = (short)f2bs(f1.x); av[5] = (short)f2bs(f1.y);
                    av[6] = (short)f2bs(f1.z); av[7] = (short)f2bs(f1.w);
                }
            }
            *(short8*)&As[row * LDK + koff] = av;
            short8 bv = *(const short8*)(BT + (size_t)(bn + row) * K + k0 + koff);
            *(short8*)&Bs[row * LDK + koff] = bv;
        }
        __syncthreads();

        short8 af[4], bf[4];
#pragma unroll
        for (int f = 0; f < 4; ++f) {
            af[f] = *(const short8*)&As[(wm + f * 16 + l15) * LDK + quad * 8];
            bf[f] = *(const short8*)&Bs[(wn + f * 16 + l15) * LDK + quad * 8];
        }
#pragma unroll
        for (int fm = 0; fm < 4; ++fm)
#pragma unroll
            for (int fn = 0; fn < 4; ++fn)
                acc[fm][fn] = __builtin_amdgcn_mfma_f32_16x16x32_bf16(
                    af[fm], bf[fn], acc[fm][fn], 0, 0, 0);
        __syncthreads();
    }

#pragma unroll
    for (int fm = 0; fm < 4; ++fm) {
#pragma unroll
        for (int r = 0; r < 4; ++r) {
            int grow = bm + wm + fm * 16 + quad * 4 + r;
            if (grow >= M) continue;
#pragma unroll
            for (int fn = 0; fn < 4; ++fn) {
                int gcol = bn + wn + fn * 16 + l15;
                store_out(C, (size_t)grow * Nn + gcol, acc[fm][fn][r]);
            }
        }
    }
}

// ---------------- attention scalar products (per node) ----------------

__global__ void alpha1_kernel(const __hip_bfloat16* __restrict__ h1,
                              const float* __restrict__ asw,
                              const float* __restrict__ adw,
                              float* __restrict__ as1, float* __restrict__ ad1,
                              int n) {
    int gt = blockIdx.x * blockDim.x + threadIdx.x;
    int v = gt >> 6;
    int lane = gt & 63;
    if (v >= n) return;
#pragma unroll
    for (int h = 0; h < HEADS; ++h) {
        float val = __bfloat162float(h1[(size_t)v * HID + h * C1 + lane]);
        float s = val * asw[h * C1 + lane];
        float d = val * adw[h * C1 + lane];
#pragma unroll
        for (int o = 32; o > 0; o >>= 1) {
            s += __shfl_down(s, o);
            d += __shfl_down(d, o);
        }
        if (lane == 0) {
            as1[v * HEADS + h] = s;
            ad1[v * HEADS + h] = d;
        }
    }
}

__global__ void alpha2_kernel(const float* __restrict__ h2,
                              const float* __restrict__ asw,
                              const float* __restrict__ adw,
                              float* __restrict__ as2, float* __restrict__ ad2,
                              int n) {
    int gt = blockIdx.x * blockDim.x + threadIdx.x;
    int v = gt >> 6;
    int lane = gt & 63;
    if (v >= n) return;
    float v0 = h2[(size_t)v * OUT_DIM + lane];
    float v1 = h2[(size_t)v * OUT_DIM + 64 + lane];
    float s = v0 * asw[lane] + v1 * asw[64 + lane];
    float d = v0 * adw[lane] + v1 * adw[64 + lane];
#pragma unroll
    for (int o = 32; o > 0; o >>= 1) {
        s += __shfl_down(s, o);
        d += __shfl_down(d, o);
    }
    if (lane == 0) { as2[v] = s; ad2[v] = d; }
}

// ---------------- edge softmax: normalized alpha per (edge, head) ---------

__global__ __launch_bounds__(256) void attn1_kernel(
    const float* __restrict__ as1, const float* __restrict__ ad1,
    const int* __restrict__ offs, const int* __restrict__ ssrc,
    float* __restrict__ alpha, int n) {
    int v = blockIdx.x * 4 + (threadIdx.x >> 6);
    if (v >= n) return;
    int l = threadIdx.x & 63;
    int h = l & 3;
    int eoff = l >> 2;
    int start = offs[v], end = offs[v + 1];
    float adv = ad1[v * 4 + h];

    float m = -1e30f;
    for (int i = start + eoff; i < end; i += 16)
        m = fmaxf(m, leaky(as1[ssrc[i] * 4 + h] + adv));
#pragma unroll
    for (int o = 4; o < 64; o <<= 1) m = fmaxf(m, __shfl_xor(m, o));

    float den = 0.f;
    for (int i = start + eoff; i < end; i += 16) {
        float w = __expf(leaky(as1[ssrc[i] * 4 + h] + adv) - m);
        alpha[(size_t)i * 4 + h] = w;
        den += w;
    }
#pragma unroll
    for (int o = 4; o < 64; o <<= 1) den += __shfl_xor(den, o);
    float r = 1.f / (den + 1e-16f);

    for (int j = start * 4 + l; j < end * 4; j += 64) alpha[j] *= r;
}

__global__ __launch_bounds__(256) void attn2_kernel(
    const float* __restrict__ as2, const float* __restrict__ ad2,
    const int* __restrict__ offs, const int* __restrict__ ssrc,
    float* __restrict__ alpha, int n) {
    int v = blockIdx.x * 4 + (threadIdx.x >> 6);
    if (v >= n) return;
    int l = threadIdx.x & 63;
    int start = offs[v], end = offs[v + 1];
    float adv = ad2[v];

    float m = -1e30f;
    for (int i = start + l; i < end; i += 64)
        m = fmaxf(m, leaky(as2[ssrc[i]] + adv));
#pragma unroll
    for (int o = 1; o < 64; o <<= 1) m = fmaxf(m, __shfl_xor(m, o));

    float den = 0.f;
    for (int i = start + l; i < end; i += 64) {
        float w = __expf(leaky(as2[ssrc[i]] + adv) - m);
        alpha[i] = w;
        den += w;
    }
#pragma unroll
    for (int o = 1; o < 64; o <<= 1) den += __shfl_xor(den, o);
    float r = 1.f / (den + 1e-16f);

    for (int i = start + l; i < end; i += 64) alpha[i] *= r;
}

// ---------------- weighted-gather aggregation (MLP-optimized) --------------

__global__ __launch_bounds__(256) void agg1v_kernel(
    const ushort4* __restrict__ h1, const float* __restrict__ alpha,
    const int* __restrict__ offs, const int* __restrict__ ssrc,
    const float* __restrict__ bias1, ushort4* __restrict__ g, int n) {
    int t = threadIdx.x & 63;
    int v = blockIdx.x * 4 + (threadIdx.x >> 6);
    if (v >= n) return;
    int head = t >> 4;
    int start = offs[v], end = offs[v + 1];

    float a0 = 0.f, a1 = 0.f, a2 = 0.f, a3 = 0.f;
    int i = start;
    for (; i + 4 <= end; i += 4) {
        int s0 = ssrc[i], s1 = ssrc[i + 1], s2 = ssrc[i + 2], s3 = ssrc[i + 3];
        float w0 = alpha[(size_t)i * 4 + head];
        float w1 = alpha[(size_t)(i + 1) * 4 + head];
        float w2 = alpha[(size_t)(i + 2) * 4 + head];
        float w3 = alpha[(size_t)(i + 3) * 4 + head];
        ushort4 p0 = h1[(size_t)s0 * 64 + t];
        ushort4 p1 = h1[(size_t)s1 * 64 + t];
        ushort4 p2 = h1[(size_t)s2 * 64 + t];
        ushort4 p3 = h1[(size_t)s3 * 64 + t];
        a0 += w0 * bs2f(p0.x) + w1 * bs2f(p1.x) + w2 * bs2f(p2.x) + w3 * bs2f(p3.x);
        a1 += w0 * bs2f(p0.y) + w1 * bs2f(p1.y) + w2 * bs2f(p2.y) + w3 * bs2f(p3.y);
        a2 += w0 * bs2f(p0.z) + w1 * bs2f(p1.z) + w2 * bs2f(p2.z) + w3 * bs2f(p3.z);
        a3 += w0 * bs2f(p0.w) + w1 * bs2f(p1.w) + w2 * bs2f(p2.w) + w3 * bs2f(p3.w);
    }
    for (; i < end; ++i) {
        int s = ssrc[i];
        float w = alpha[(size_t)i * 4 + head];
        ushort4 p = h1[(size_t)s * 64 + t];
        a0 += w * bs2f(p.x);
        a1 += w * bs2f(p.y);
        a2 += w * bs2f(p.z);
        a3 += w * bs2f(p.w);
    }
    float4 bq = *(const float4*)&bias1[4 * t];
    float o0 = a0 + bq.x, o1 = a1 + bq.y, o2 = a2 + bq.z, o3 = a3 + bq.w;
    o0 = 0.5f * o0 * (1.0f + erff(o0 * 0.70710678f));
    o1 = 0.5f * o1 * (1.0f + erff(o1 * 0.70710678f));
    o2 = 0.5f * o2 * (1.0f + erff(o2 * 0.70710678f));
    o3 = 0.5f * o3 * (1.0f + erff(o3 * 0.70710678f));
    ushort4 r;
    r.x = f2bs(o0); r.y = f2bs(o1); r.z = f2bs(o2); r.w = f2bs(o3);
    g[(size_t)v * 64 + t] = r;
}

__global__ __launch_bounds__(256) void agg2v_kernel(
    const float2* __restrict__ h2, const float* __restrict__ alpha,
    const int* __restrict__ offs, const int* __restrict__ ssrc,
    const float* __restrict__ bias2, void* __restrict__ out,
    const int* outflagp, int n) {
    int t = threadIdx.x & 63;
    int v = blockIdx.x * 4 + (threadIdx.x >> 6);
    if (v >= n) return;
    int start = offs[v], end = offs[v + 1];

    float nx = 0.f, ny = 0.f;
    int i = start;
    for (; i + 4 <= end; i += 4) {
        int s0 = ssrc[i], s1 = ssrc[i + 1], s2 = ssrc[i + 2], s3 = ssrc[i + 3];
        float w0 = alpha[i], w1 = alpha[i + 1], w2 = alpha[i + 2], w3 = alpha[i + 3];
        float2 p0 = h2[(size_t)s0 * 64 + t];
        float2 p1 = h2[(size_t)s1 * 64 + t];
        float2 p2 = h2[(size_t)s2 * 64 + t];
        float2 p3 = h2[(size_t)s3 * 64 + t];
        nx += w0 * p0.x + w1 * p1.x + w2 * p2.x + w3 * p3.x;
        ny += w0 * p0.y + w1 * p1.y + w2 * p2.y + w3 * p3.y;
    }
    for (; i < end; ++i) {
        int s = ssrc[i];
        float w = alpha[i];
        float2 p = h2[(size_t)s * 64 + t];
        nx += w * p.x;
        ny += w * p.y;
    }
    float ox = nx + bias2[2 * t];
    float oy = ny + bias2[2 * t + 1];
    size_t oi = (size_t)v * 64 + t;
    if (*outflagp) {
        __hip_bfloat162 r;
        r.x = __float2bfloat16(ox);
        r.y = __float2bfloat16(oy);
        ((__hip_bfloat162*)out)[oi] = r;
    } else {
        ((float2*)out)[oi] = make_float2(ox, oy);
    }
}

// ---------------------------------------------------------------------------

static inline char* alignp(char* p, size_t a) {
    return (char*)(((uintptr_t)p + a - 1) & ~(uintptr_t)(a - 1));
}

extern "C" void kernel_launch(void* const* d_in, const int* in_sizes, int n_in,
                              void* d_out, int out_size, void* d_ws, size_t ws_size,
                              hipStream_t stream) {
    const void* x    = d_in[0];
    const int*  ei   = (const int*)d_in[1];
    const void* W1   = d_in[2];
    const void* as1w = d_in[3];
    const void* ad1w = d_in[4];
    const void* b1   = d_in[5];
    const void* W2   = d_in[6];
    const void* as2w = d_in[7];
    const void* ad2w = d_in[8];
    const void* b2   = d_in[9];

    const int N  = out_size / OUT_DIM;       // 50000
    const int E  = in_sizes[1] / 2;          // 800000
    const int EP = E + N;
    const int NB = (N + 255) / 256;          // scan blocks (196)

    // ---- workspace carve (~74.2 MB; h1/h2 union) ----
    char* p = (char*)d_ws;
    __hip_bfloat16* h1 = (__hip_bfloat16*)p;
    float*          h2 = (float*)p;           p += (size_t)N * HID * 2;
    __hip_bfloat16* g  = (__hip_bfloat16*)p;  p += (size_t)N * HID * 2;
    float* as1wf = (float*)p;                 p += 256 * 4;
    float* ad1wf = (float*)p;                 p += 256 * 4;
    float* b1f   = (float*)p;                 p += 256 * 4;
    float* as2wf = (float*)p;                 p += 128 * 4;
    float* ad2wf = (float*)p;                 p += 128 * 4;
    float* b2f   = (float*)p;                 p += 128 * 4;
    float* as1   = (float*)p;                 p += (size_t)N * HEADS * 4;
    float* ad1   = (float*)p;                 p += (size_t)N * HEADS * 4;
    float* as2   = (float*)p;                 p += (size_t)N * 4;
    float* ad2   = (float*)p;                 p += (size_t)N * 4;
    float* al1   = (float*)p;                 p += (size_t)EP * HEADS * 4;
    float* al2   = (float*)p;                 p += (size_t)EP * 4;
    int*   flags = (int*)p;                   p += 16 * 4;
    int*   deg   = (int*)p;                   p += (size_t)N * 4;
    int*   offs  = (int*)p;                   p += (size_t)(N + 1) * 4;
    int*   bsum  = (int*)p;                   p += (size_t)1024 * 4;
    int*   ssrc  = (int*)p;                   p += (size_t)EP * 4;
    p = alignp(p, 64);
    __hip_bfloat16* W1T = (__hip_bfloat16*)p; p += (size_t)HID * IN_DIM * 2;
    __hip_bfloat16* W2T = (__hip_bfloat16*)p; p += (size_t)OUT_DIM * HID * 2;

    // ---- prep ----
    prep_kernel<<<9, 256, 0, stream>>>(x, in_sizes[0], W1, as1w, ad1w, b1,
                                       W2, as2w, ad2w, b2,
                                       as1wf, ad1wf, b1f, as2wf, ad2wf, b2f,
                                       flags);
    tpose_kernel<<<384, 256, 0, stream>>>(W1, W2, flags, W1T, W2T);

    // ---- CSR build (multi-block scan) ----
    hipMemsetAsync(deg, 0, (size_t)N * sizeof(int), stream);
    {
        int blk = 256, grd = (EP + blk - 1) / blk;
        count_kernel<<<grd, blk, 0, stream>>>(ei, E, EP, deg);
        psum_kernel<<<NB, 256, 0, stream>>>(deg, bsum, N);
        bscan_kernel<<<1, 1024, 0, stream>>>(bsum, NB);
        wscan_kernel<<<NB, 256, 0, stream>>>(deg, bsum, offs, N);
        fill_kernel<<<grd, blk, 0, stream>>>(ei, E, EP, deg, ssrc);
    }

    // ---- layer 1 ----
    gemm_mfma<__hip_bfloat16><<<dim3(HID / 128, (N + 127) / 128), 256, 0, stream>>>(
        x, flags + 0, W1T, h1, N, HID, IN_DIM);
    alpha1_kernel<<<((N * 64) + 255) / 256, 256, 0, stream>>>(h1, as1wf, ad1wf, as1, ad1, N);
    attn1_kernel<<<(N + 3) / 4, 256, 0, stream>>>(as1, ad1, offs, ssrc, al1, N);
    agg1v_kernel<<<(N + 3) / 4, 256, 0, stream>>>((const ushort4*)h1, al1, offs, ssrc,
                                                  b1f, (ushort4*)g, N);

    // ---- layer 2 (h2 reuses h1's buffer) ----
    gemm_mfma<float><<<dim3(OUT_DIM / 128, (N + 127) / 128), 256, 0, stream>>>(
        g, nullptr, W2T, h2, N, OUT_DIM, HID);
    alpha2_kernel<<<((N * 64) + 255) / 256, 256, 0, stream>>>(h2, as2wf, ad2wf, as2, ad2, N);
    attn2_kernel<<<(N + 3) / 4, 256, 0, stream>>>(as2, ad2, offs, ssrc, al2, N);
    agg2v_kernel<<<(N + 3) / 4, 256, 0, stream>>>((const float2*)h2, al2, offs, ssrc,
                                                  b2f, d_out, flags + 0, N);
}